// Round 13
// baseline (555.451 us; speedup 1.0000x reference)
//
#include <hip/hip_runtime.h>
#include <hip/hip_bf16.h>
#include <cmath>

// ---------------------------------------------------------------------------
// Problem constants (fixed shapes)
// ---------------------------------------------------------------------------
constexpr int cNE = 100000, cNT = 1024, cNC = 128, cD = 128, cNR = 500;
constexpr int cB = 512, cNSRC = 4096, cT = 1024, cE = 4;
constexpr int cNNZ_E2T = 1000000, cNNZ_T2C = 50000, cNNZ_E2C = 500000;
constexpr float cDECAY = 1e-4f, cCLW = 0.1f;
constexpr int cNN_E2T = cNE + cNT;     // 101024
constexpr int cNN_E2C = cNE + cNC;     // 100128
constexpr int cNN_T2C = cNT + cNC;     // 1152

// ---------------------------------------------------------------------------
// Workspace layout (FLOAT units)
// ---------------------------------------------------------------------------
constexpr size_t F_S1   = 0;                          // f32 4096x128
constexpr size_t F_S2   = F_S1 + 524288;
constexpr size_t F_PT   = F_S2 + 524288;              // bf16 W [8192][128]
constexpr size_t F_Z1   = F_PT + 524288;              // bf16 P1
constexpr size_t F_Z2   = F_Z1 + 524288;              // bf16 SB
constexpr size_t F_MSG  = F_Z2 + 524288;              // bf16 4096x256
constexpr size_t F_GATE = F_MSG + 524288;             // f32 GSUM [512][4]
constexpr size_t F_SCAL = F_GATE + 16384;
constexpr size_t F_RS   = F_SCAL + 64;                // f32 [2][8192]
constexpr size_t F_D11  = F_RS + 16384;
constexpr size_t F_D12  = F_D11 + 4096;
constexpr size_t F_D22  = F_D12 + 4096;
constexpr size_t F_U    = F_D22 + 4096;               // union base
// --- GCN phase ---
constexpr size_t G_X1F  = F_U;                        // ushort[101024*128]
constexpr size_t G_X2C  = G_X1F + 6465536;            // ushort[4096*128] (also MARK)
constexpr size_t G_SLOT = G_X2C + 262144;
constexpr size_t G_REP  = G_SLOT + 101376;
constexpr size_t G_RP   = G_REP + 4096;
constexpr size_t G_FILL = G_RP + 101376;
constexpr size_t G_COLS = G_FILL + 101376;
constexpr size_t G_VALS = G_COLS + 1000000;
constexpr size_t G_X1T  = G_VALS + 1000000;
constexpr size_t G_X2T  = G_X1T + 73728;
constexpr size_t G_BSUM = G_X2T + 73728;              // int[512]
constexpr size_t G_EBF  = G_BSUM + 512;               // ushort[100000*128]
constexpr size_t G_TBF  = G_EBF + 3200000;
constexpr size_t G_CBF  = G_TBF + 65536;
// --- activation phase ---
constexpr size_t A_U0  = F_U;
constexpr size_t A_U1  = F_U + 2097152;
constexpr size_t A_WBT = F_U + 4 * 2097152;

typedef __attribute__((ext_vector_type(8))) short short8v;
typedef __attribute__((ext_vector_type(4))) float f32x4;

// ---------------------------------------------------------------------------
// Helpers
// ---------------------------------------------------------------------------
__device__ __forceinline__ void atomAdd(float* p, float v) {
  __hip_atomic_fetch_add(p, v, __ATOMIC_RELAXED, __HIP_MEMORY_SCOPE_AGENT);
}
__device__ __forceinline__ ushort f2bf(float f) {
  __hip_bfloat16 h = __float2bfloat16(f);
  return *reinterpret_cast<ushort*>(&h);
}
__device__ __forceinline__ float bf2f(ushort u) {
  __hip_bfloat16 h; *reinterpret_cast<ushort*>(&h) = u;
  return __bfloat162float(h);
}

__device__ __forceinline__ int mapNode(int mode, int id) {
  switch (mode) {
    case 0:  return (id < cNE + cNT) ? id : -1;
    case 1:  return (id >= cNE + cNT) ? (id - cNE) : -1;
    case 2:  return (id >= cNE && id < cNE + cNT) ? (id - cNE) : -1;
    default: return (id < cNE) ? id
                   : ((id >= cNE + cNT) ? (id - cNT) : -1);
  }
}

__device__ __forceinline__ float blockReduce256(float v, float* sh, int tid) {
  sh[tid] = v; __syncthreads();
  for (int s = 128; s > 0; s >>= 1) {
    if (tid < s) sh[tid] += sh[tid + s];
    __syncthreads();
  }
  float r = sh[0]; __syncthreads();
  return r;
}

// ---------------------------------------------------------------------------
// f32 -> bf16 table conversion (grid-stride over quads)
// ---------------------------------------------------------------------------
__global__ __launch_bounds__(256) void k_to_bf(const float* __restrict__ src,
                                               ushort* __restrict__ dst, int nq) {
  for (int q = blockIdx.x * 256 + threadIdx.x; q < nq; q += gridDim.x * 256) {
    float4 v = *reinterpret_cast<const float4*>(src + (size_t)q * 4);
    ushort4 o;
    o.x = f2bf(v.x); o.y = f2bf(v.y); o.z = f2bf(v.z); o.w = f2bf(v.w);
    *reinterpret_cast<ushort4*>(dst + (size_t)q * 4) = o;
  }
}

// pack bq|bk|bv into one 3072-float buffer
__global__ __launch_bounds__(256) void k_pack_bias(const float* __restrict__ b0,
                                                   const float* __restrict__ b1,
                                                   const float* __restrict__ b2,
                                                   float* __restrict__ dst) {
  int i = blockIdx.x * 256 + threadIdx.x;   // 3072 total
  float v = (i < 1024) ? b0[i] : (i < 2048) ? b1[i - 1024] : b2[i - 2048];
  dst[i] = v;
}

// ---------------------------------------------------------------------------
// init + mask + CSR build
// ---------------------------------------------------------------------------
__global__ __launch_bounds__(256) void k_init3(int* __restrict__ slot, int* __restrict__ mark,
                                               int* __restrict__ fill, int n) {
  int i = blockIdx.x * 256 + threadIdx.x;
  if (i < n) { slot[i] = 0x7f7f7f7f; mark[i] = 0; fill[i] = 0; }
}

__global__ __launch_bounds__(256) void k_slot_mark(const int* __restrict__ ids,
                                                   int* __restrict__ slot,
                                                   int* __restrict__ mark, int mode) {
  int i = blockIdx.x * 256 + threadIdx.x;
  if (i >= cNSRC) return;
  int node = mapNode(mode, ids[i]);
  if (node >= 0) { atomicMin(&slot[node], i); mark[node] = 1; }
}

__global__ __launch_bounds__(256) void k_mark_edges(const int* __restrict__ row,
                                                    const int* __restrict__ col, int nnz,
                                                    const int* __restrict__ slot,
                                                    int* __restrict__ mark) {
  int e = blockIdx.x * 256 + threadIdx.x;
  if (e >= nnz) return;
  int r = row[e];
  if (slot[r] < cNSRC) mark[col[e]] = 1;
}

__global__ __launch_bounds__(256) void k_hist(const int* __restrict__ row, int nnz,
                                              const int* __restrict__ mark,
                                              int* __restrict__ cnt) {
  int e = blockIdx.x * 256 + threadIdx.x;
  if (e >= nnz) return;
  int r = row[e];
  if (mark && !mark[r]) return;
  atomicAdd(&cnt[r], 1);
}

__global__ __launch_bounds__(256) void k_scan_block(const int* __restrict__ cnt, int n,
                                                    int* __restrict__ excl, int* __restrict__ bsum) {
  __shared__ int sh[256];
  int tid = threadIdx.x;
  int i = blockIdx.x * 256 + tid;
  int v = (i < n) ? cnt[i] : 0;
  sh[tid] = v; __syncthreads();
  for (int off = 1; off < 256; off <<= 1) {
    int t = (tid >= off) ? sh[tid - off] : 0;
    __syncthreads();
    sh[tid] += t;
    __syncthreads();
  }
  if (i < n) excl[i] = sh[tid] - v;
  if (tid == 255) bsum[blockIdx.x] = sh[255];
}

__global__ __launch_bounds__(512) void k_bsum_scan(int* __restrict__ bsum, int nb,
                                                   int* __restrict__ rowptr, int n) {
  __shared__ int sh[512];
  int tid = threadIdx.x;
  int v = (tid < nb) ? bsum[tid] : 0;
  sh[tid] = v; __syncthreads();
  for (int off = 1; off < 512; off <<= 1) {
    int t = (tid >= off) ? sh[tid - off] : 0;
    __syncthreads();
    sh[tid] += t;
    __syncthreads();
  }
  if (tid < nb) bsum[tid] = sh[tid] - v;
  if (tid == 511) rowptr[n] = sh[511];
}

__global__ __launch_bounds__(256) void k_scan_add(int* __restrict__ rowptr,
                                                  const int* __restrict__ bsum, int n,
                                                  int* __restrict__ fill) {
  int i = blockIdx.x * 256 + threadIdx.x;
  if (i < n) {
    int r = rowptr[i] + bsum[blockIdx.x];
    rowptr[i] = r;
    fill[i] = r;
  }
}

__global__ __launch_bounds__(256) void k_fill(const int* __restrict__ row,
                                              const int* __restrict__ col,
                                              const float* __restrict__ val, int nnz,
                                              const int* __restrict__ mark,
                                              int* __restrict__ fill,
                                              int* __restrict__ cols, float* __restrict__ vals) {
  int e = blockIdx.x * 256 + threadIdx.x;
  if (e >= nnz) return;
  int r = row[e];
  if (mark && !mark[r]) return;
  int pos = atomicAdd(&fill[r], 1);
  cols[pos] = col[e];
  vals[pos] = val[e];
}

// wave-per-row gather, bf16 tables in -> bf16 out (4-wide unrolled)
__global__ __launch_bounds__(256) void k_gather(
    const int* __restrict__ rowptr, const int* __restrict__ cols, const float* __restrict__ vals,
    const ushort* __restrict__ ea, const ushort* __restrict__ eb, int na,
    int nrows, const int* __restrict__ mark, ushort* __restrict__ out) {
  int r = blockIdx.x * 4 + (threadIdx.x >> 6);
  if (r >= nrows) return;
  if (mark && !mark[r]) return;
  int lane = threadIdx.x & 63;
  int p0 = rowptr[r], p1 = rowptr[r + 1];
  float ax = 0.f, ay = 0.f;
  int p = p0;
  for (; p + 4 <= p1; p += 4) {
    int c0 = cols[p], c1 = cols[p + 1], c2 = cols[p + 2], c3 = cols[p + 3];
    float v0 = vals[p], v1 = vals[p + 1], v2 = vals[p + 2], v3 = vals[p + 3];
    const ushort* s0 = (c0 < na) ? (ea + (size_t)c0 * cD) : (eb + (size_t)(c0 - na) * cD);
    const ushort* s1 = (c1 < na) ? (ea + (size_t)c1 * cD) : (eb + (size_t)(c1 - na) * cD);
    const ushort* s2 = (c2 < na) ? (ea + (size_t)c2 * cD) : (eb + (size_t)(c2 - na) * cD);
    const ushort* s3 = (c3 < na) ? (ea + (size_t)c3 * cD) : (eb + (size_t)(c3 - na) * cD);
    ushort2 x0 = *reinterpret_cast<const ushort2*>(s0 + lane * 2);
    ushort2 x1 = *reinterpret_cast<const ushort2*>(s1 + lane * 2);
    ushort2 x2 = *reinterpret_cast<const ushort2*>(s2 + lane * 2);
    ushort2 x3 = *reinterpret_cast<const ushort2*>(s3 + lane * 2);
    ax += v0 * bf2f(x0.x) + v1 * bf2f(x1.x) + v2 * bf2f(x2.x) + v3 * bf2f(x3.x);
    ay += v0 * bf2f(x0.y) + v1 * bf2f(x1.y) + v2 * bf2f(x2.y) + v3 * bf2f(x3.y);
  }
  for (; p < p1; ++p) {
    int c = cols[p];
    float v = vals[p];
    const ushort* s = (c < na) ? (ea + (size_t)c * cD) : (eb + (size_t)(c - na) * cD);
    ushort2 x = *reinterpret_cast<const ushort2*>(s + lane * 2);
    ax += v * bf2f(x.x); ay += v * bf2f(x.y);
  }
  ushort2 o; o.x = f2bf(ax); o.y = f2bf(ay);
  *reinterpret_cast<ushort2*>(out + (size_t)r * cD + lane * 2) = o;
}

__global__ __launch_bounds__(256) void k_rep(const int* __restrict__ ids,
                                             const int* __restrict__ slot, int mode,
                                             int* __restrict__ rep) {
  int i = blockIdx.x * 256 + threadIdx.x;
  if (i >= cNSRC) return;
  int node = mapNode(mode, ids[i]);
  rep[i] = (node >= 0 && slot[node] == i) ? node : -1;
}

// layer-2 gather at representative slots (4-wide unrolled)
__global__ __launch_bounds__(256) void k_gather_slot(
    const int* __restrict__ rowptr, const int* __restrict__ cols, const float* __restrict__ vals,
    const ushort* __restrict__ x1, const int* __restrict__ rep,
    ushort* __restrict__ outc) {
  int i = blockIdx.x * 4 + (threadIdx.x >> 6);
  if (i >= cNSRC) return;
  int r = rep[i];
  if (r < 0) return;
  int lane = threadIdx.x & 63;
  int p0 = rowptr[r], p1 = rowptr[r + 1];
  float ax = 0.f, ay = 0.f;
  int p = p0;
  for (; p + 4 <= p1; p += 4) {
    int c0 = cols[p], c1 = cols[p + 1], c2 = cols[p + 2], c3 = cols[p + 3];
    float v0 = vals[p], v1 = vals[p + 1], v2 = vals[p + 2], v3 = vals[p + 3];
    ushort2 x0 = *reinterpret_cast<const ushort2*>(x1 + (size_t)c0 * cD + lane * 2);
    ushort2 x1v = *reinterpret_cast<const ushort2*>(x1 + (size_t)c1 * cD + lane * 2);
    ushort2 x2 = *reinterpret_cast<const ushort2*>(x1 + (size_t)c2 * cD + lane * 2);
    ushort2 x3 = *reinterpret_cast<const ushort2*>(x1 + (size_t)c3 * cD + lane * 2);
    ax += v0 * bf2f(x0.x) + v1 * bf2f(x1v.x) + v2 * bf2f(x2.x) + v3 * bf2f(x3.x);
    ay += v0 * bf2f(x0.y) + v1 * bf2f(x1v.y) + v2 * bf2f(x2.y) + v3 * bf2f(x3.y);
  }
  for (; p < p1; ++p) {
    int c = cols[p];
    float v = vals[p];
    ushort2 x = *reinterpret_cast<const ushort2*>(x1 + (size_t)c * cD + lane * 2);
    ax += v * bf2f(x.x); ay += v * bf2f(x.y);
  }
  ushort2 o; o.x = f2bf(ax); o.y = f2bf(ay);
  *reinterpret_cast<ushort2*>(outc + (size_t)i * cD + lane * 2) = o;
}

// full-row gather, bf16 in -> bf16 out (t2c layer 2)
__global__ __launch_bounds__(256) void k_gather_bf(
    const int* __restrict__ rowptr, const int* __restrict__ cols, const float* __restrict__ vals,
    const ushort* __restrict__ x1, int nrows, ushort* __restrict__ out) {
  int r = blockIdx.x * 4 + (threadIdx.x >> 6);
  if (r >= nrows) return;
  int lane = threadIdx.x & 63;
  int p0 = rowptr[r], p1 = rowptr[r + 1];
  float ax = 0.f, ay = 0.f;
  for (int p = p0; p < p1; ++p) {
    int c = cols[p];
    float v = vals[p];
    ushort2 x = *reinterpret_cast<const ushort2*>(x1 + (size_t)c * cD + lane * 2);
    ax += v * bf2f(x.x); ay += v * bf2f(x.y);
  }
  ushort2 o; o.x = f2bf(ax); o.y = f2bf(ay);
  *reinterpret_cast<ushort2*>(out + (size_t)r * cD + lane * 2) = o;
}

// (x0 + x1 + x2)/3 at gathered rows -> LayerNorm -> dst (x1,x2 bf16)
__global__ __launch_bounds__(128) void gather_ln(
    const int* __restrict__ ids, int mode,
    const float* __restrict__ ea, const float* __restrict__ eb, int na,
    const ushort* __restrict__ x1, const ushort* __restrict__ x2, const int* __restrict__ slot,
    const float* __restrict__ g, const float* __restrict__ bia, float* __restrict__ dst) {
  __shared__ float shx[2], shy[2];
  int i = blockIdx.x;
  int tid = threadIdx.x;
  int id = ids[i];
  int node = mapNode(mode, id);
  if (node < 0) return;
  const float* x0 = (node < na) ? (ea + (size_t)node * cD) : (eb + (size_t)(node - na) * cD);
  int xi2 = slot ? slot[node] : node;
  float a = (x0[tid] + bf2f(x1[(size_t)node * cD + tid]) + bf2f(x2[(size_t)xi2 * cD + tid]))
            * (1.0f / 3.0f);
  float sx = a, sy = a * a;
#pragma unroll
  for (int off = 32; off > 0; off >>= 1) {
    sx += __shfl_xor(sx, off);
    sy += __shfl_xor(sy, off);
  }
  if ((tid & 63) == 0) { shx[tid >> 6] = sx; shy[tid >> 6] = sy; }
  __syncthreads();
  float s  = shx[0] + shx[1];
  float ss = shy[0] + shy[1];
  float mu = s * (1.0f / 128.0f);
  float var = ss * (1.0f / 128.0f) - mu * mu;
  float y = (a - mu) * rsqrtf(var + 1e-5f) * g[tid] + bia[tid];
  dst[(size_t)i * cD + tid] = y;
}

// ---------------------------------------------------------------------------
// bf16 MFMA GEMM device body (shared by gemm_bf and the fused kernel)
// ---------------------------------------------------------------------------
__device__ __forceinline__ void gemm_bf_body(
    ushort* As, ushort* Bs, int bx, int by,
    const ushort* __restrict__ A, const ushort* __restrict__ Bt,
    int N, int K, const float* __restrict__ bias, ushort* __restrict__ Cbf, int epi) {
  const int t = threadIdx.x;
  const int wv = t >> 6, lane = t & 63;
  const int wr = (wv >> 1) * 64, wc = (wv & 1) * 64;
  const int srow = t >> 1, shalf = t & 1;
  const ushort* Ag = A + (size_t)(by * 128 + srow) * K + shalf * 16;
  const ushort* Bg = Bt + (size_t)(bx * 128 + srow) * K + shalf * 16;
  uint4 ra0 = *reinterpret_cast<const uint4*>(Ag);
  uint4 ra1 = *reinterpret_cast<const uint4*>(Ag + 8);
  uint4 rb0 = *reinterpret_cast<const uint4*>(Bg);
  uint4 rb1 = *reinterpret_cast<const uint4*>(Bg + 8);
  f32x4 acc[4][4];
  const f32x4 z4 = {0.f, 0.f, 0.f, 0.f};
#pragma unroll
  for (int i = 0; i < 4; ++i)
#pragma unroll
    for (int j = 0; j < 4; ++j) acc[i][j] = z4;
  const int la = lane & 15, lk = (lane >> 4) * 8;
  const int sdst = srow * 40 + shalf * 16;
  for (int kt = 0; kt < K; kt += 32) {
    __syncthreads();
    *reinterpret_cast<uint4*>(&As[sdst])     = ra0;
    *reinterpret_cast<uint4*>(&As[sdst + 8]) = ra1;
    *reinterpret_cast<uint4*>(&Bs[sdst])     = rb0;
    *reinterpret_cast<uint4*>(&Bs[sdst + 8]) = rb1;
    __syncthreads();
    if (kt + 32 < K) {
      ra0 = *reinterpret_cast<const uint4*>(Ag + kt + 32);
      ra1 = *reinterpret_cast<const uint4*>(Ag + kt + 40);
      rb0 = *reinterpret_cast<const uint4*>(Bg + kt + 32);
      rb1 = *reinterpret_cast<const uint4*>(Bg + kt + 40);
    }
    short8v af[4], bfr[4];
#pragma unroll
    for (int i = 0; i < 4; ++i)
      af[i] = *reinterpret_cast<const short8v*>(&As[(wr + i * 16 + la) * 40 + lk]);
#pragma unroll
    for (int j = 0; j < 4; ++j)
      bfr[j] = *reinterpret_cast<const short8v*>(&Bs[(wc + j * 16 + la) * 40 + lk]);
#pragma unroll
    for (int i = 0; i < 4; ++i)
#pragma unroll
      for (int j = 0; j < 4; ++j)
        acc[i][j] = __builtin_amdgcn_mfma_f32_16x16x32_bf16(af[i], bfr[j], acc[i][j], 0, 0, 0);
  }
  const int r0 = by * 128 + wr + (lane >> 4) * 4;
  const int c0 = bx * 128 + wc + la;
#pragma unroll
  for (int i = 0; i < 4; ++i)
#pragma unroll
    for (int j = 0; j < 4; ++j) {
      int c = c0 + j * 16;
      float bv = bias[c];
#pragma unroll
      for (int q = 0; q < 4; ++q) {
        int r = r0 + i * 16 + q;
        float v = acc[i][j][q] + bv;
        if (epi == 1) v = (v > 0.0f) ? v : expm1f(v);
        Cbf[(size_t)r * N + c] = f2bf(v);
      }
    }
}

__global__ __launch_bounds__(256) void gemm_bf(
    const ushort* __restrict__ A, const ushort* __restrict__ Bt,
    int N, int K, const float* __restrict__ bias, ushort* __restrict__ Cbf, int epi) {
  __shared__ ushort As[128 * 40];
  __shared__ ushort Bs[128 * 40];
  gemm_bf_body(As, Bs, blockIdx.x, blockIdx.y, A, Bt, N, K, bias, Cbf, epi);
}

// ---------------------------------------------------------------------------
// gram_sym device body (proven r8/r10 form)
// ---------------------------------------------------------------------------
__device__ __forceinline__ void gram_body(
    ushort* As, ushort* Bs, int tileIdx,
    const ushort* __restrict__ W, float* __restrict__ rsum,
    float* __restrict__ d11, float* __restrict__ d12, float* __restrict__ d22) {
  int tt = tileIdx, bi = 0, cnt = 64;
  while (tt >= cnt) { tt -= cnt; ++bi; --cnt; }
  int bj = bi + tt;
  const bool diag = (bi == bj);
  const int t = threadIdx.x;
  const int wv = t >> 6, lane = t & 63;
  const int wr = (wv >> 1) * 64, wc = (wv & 1) * 64;
  const int srow = t >> 1, shalf = t & 1;
  const ushort* Ag = W + (size_t)(bi * 128 + srow) * 128 + shalf * 16;
  const ushort* Bg = W + (size_t)(bj * 128 + srow) * 128 + shalf * 16;
  uint4 ra0 = *reinterpret_cast<const uint4*>(Ag);
  uint4 ra1 = *reinterpret_cast<const uint4*>(Ag + 8);
  uint4 rb0 = *reinterpret_cast<const uint4*>(Bg);
  uint4 rb1 = *reinterpret_cast<const uint4*>(Bg + 8);
  f32x4 acc[4][4];
  const f32x4 z4 = {0.f, 0.f, 0.f, 0.f};
#pragma unroll
  for (int i = 0; i < 4; ++i)
#pragma unroll
    for (int j = 0; j < 4; ++j) acc[i][j] = z4;
  const int la = lane & 15, lk = (lane >> 4) * 8;
  const int sdst = srow * 40 + shalf * 16;
  for (int kt = 0; kt < 128; kt += 32) {
    __syncthreads();
    *reinterpret_cast<uint4*>(&As[sdst])     = ra0;
    *reinterpret_cast<uint4*>(&As[sdst + 8]) = ra1;
    *reinterpret_cast<uint4*>(&Bs[sdst])     = rb0;
    *reinterpret_cast<uint4*>(&Bs[sdst + 8]) = rb1;
    __syncthreads();
    if (kt + 32 < 128) {
      ra0 = *reinterpret_cast<const uint4*>(Ag + kt + 32);
      ra1 = *reinterpret_cast<const uint4*>(Ag + kt + 40);
      rb0 = *reinterpret_cast<const uint4*>(Bg + kt + 32);
      rb1 = *reinterpret_cast<const uint4*>(Bg + kt + 40);
    }
    short8v af[4], bfr[4];
#pragma unroll
    for (int i = 0; i < 4; ++i)
      af[i] = *reinterpret_cast<const short8v*>(&As[(wr + i * 16 + la) * 40 + lk]);
#pragma unroll
    for (int j = 0; j < 4; ++j)
      bfr[j] = *reinterpret_cast<const short8v*>(&Bs[(wc + j * 16 + la) * 40 + lk]);
#pragma unroll
    for (int i = 0; i < 4; ++i)
#pragma unroll
      for (int j = 0; j < 4; ++j)
        acc[i][j] = __builtin_amdgcn_mfma_f32_16x16x32_bf16(af[i], bfr[j], acc[i][j], 0, 0, 0);
  }
  const int r0 = bi * 128 + wr + (lane >> 4) * 4;
  const int c0 = bj * 128 + wc + la;
  constexpr float K2 = 2.8853900817779268f;   // 2 / ln(2)
  float rs[4][4];
  float cs[4] = {0.f, 0.f, 0.f, 0.f};
#pragma unroll
  for (int i = 0; i < 4; ++i)
#pragma unroll
    for (int q = 0; q < 4; ++q) rs[i][q] = 0.f;
#pragma unroll
  for (int i = 0; i < 4; ++i)
#pragma unroll
    for (int j = 0; j < 4; ++j)
#pragma unroll
      for (int q = 0; q < 4; ++q) {
        int r = r0 + i * 16 + q;
        int c = c0 + j * 16;
        float e = exp2f(K2 * acc[i][j][q]);
        rs[i][q] += e;
        cs[j] += e;
        if (c == r)        { if (r < 4096) d11[r] = e; else d22[r - 4096] = e; }
        if (c == r + 4096) d12[r] = e;
      }
#pragma unroll
  for (int m = 1; m < 16; m <<= 1)
#pragma unroll
    for (int i = 0; i < 4; ++i)
#pragma unroll
      for (int q = 0; q < 4; ++q) rs[i][q] += __shfl_xor(rs[i][q], m);
  float* rowdst = rsum + ((bj >= 32) ? 8192 : 0);
  if (la == 0) {
#pragma unroll
    for (int i = 0; i < 4; ++i)
#pragma unroll
      for (int q = 0; q < 4; ++q) atomAdd(&rowdst[r0 + i * 16 + q], rs[i][q]);
  }
  if (!diag) {
#pragma unroll
    for (int j = 0; j < 4; ++j) {
      cs[j] += __shfl_xor(cs[j], 16);
      cs[j] += __shfl_xor(cs[j], 32);
    }
    float* coldst = rsum + ((bi >= 32) ? 8192 : 0);
    if ((lane >> 4) == 0) {
#pragma unroll
      for (int j = 0; j < 4; ++j) atomAdd(&coldst[c0 + j * 16], cs[j]);
    }
  }
}

// ---------------------------------------------------------------------------
// Fused gram + QKV, INTERLEAVED: 2848 = 32 groups x 89 blocks.
// In each group: first 24 -> QKV tile, remaining 65 -> gram tile.
// Keeps ~27% MFMA-dense QKV blocks co-resident with latency-bound gram
// blocks at every point of the dispatch.
// ---------------------------------------------------------------------------
__global__ __launch_bounds__(256) void k_gram_qkv(
    const ushort* __restrict__ W, float* __restrict__ rsum,
    float* __restrict__ d11, float* __restrict__ d12, float* __restrict__ d22,
    const ushort* __restrict__ A, const ushort* __restrict__ Bt,
    const float* __restrict__ bias, ushort* __restrict__ C) {
  __shared__ ushort As[128 * 40];
  __shared__ ushort Bs[128 * 40];
  int g = blockIdx.x / 89;
  int r = blockIdx.x % 89;
  if (r < 24) {
    int q = g * 24 + r;         // 768 QKV tiles: 24 cols x 32 rows
    gemm_bf_body(As, Bs, q % 24, q / 24, A, Bt, 3072, 1024, bias, C, 0);
  } else {
    int tile = g * 65 + (r - 24);   // 2080 gram tiles
    gram_body(As, Bs, tile, W, rsum, d11, d12, d22);
  }
}

__global__ __launch_bounds__(256) void cl_row(
    const float* __restrict__ rsum, const float* __restrict__ d11,
    const float* __restrict__ d12, const float* __restrict__ d22,
    float* __restrict__ cl_sum) {
  __shared__ float sh[256];
  int i = blockIdx.x * 256 + threadIdx.x;
  float denA = rsum[i] + rsum[8192 + i] - d11[i];
  float denB = rsum[8192 + 4096 + i] + rsum[4096 + i] - d22[i];
  float l = 0.5f * (logf(denA) + logf(denB)) - logf(d12[i]);
  float s = blockReduce256(l, sh, threadIdx.x);
  if (threadIdx.x == 0) atomAdd(cl_sum, s);
}

// ---------------------------------------------------------------------------
// Fused gate + pooling (per mailbox)
// ---------------------------------------------------------------------------
__global__ __launch_bounds__(256) void k_gate_pool(
    const ushort* __restrict__ o, const float* __restrict__ gw,
    ushort* __restrict__ ae, float* __restrict__ gsum) {
  __shared__ float os[8][1024];
  __shared__ float lg[8][4];
  __shared__ float gs[8][4];
  const int b = blockIdx.x, t = threadIdx.x;
  for (int u = t; u < 8192; u += 256) {
    int l = u >> 10, d = u & 1023;
    os[l][d] = bf2f(o[(size_t)(b * 8 + l) * 1024 + d]);
  }
  __syncthreads();
  {
    int p = t >> 3, sub = t & 7;
    int l = p >> 2, e = p & 3;
    float s = 0;
    for (int d = sub; d < 1024; d += 8) s += os[l][d] * gw[d * 4 + e];
    s += __shfl_down(s, 4, 8);
    s += __shfl_down(s, 2, 8);
    s += __shfl_down(s, 1, 8);
    if (sub == 0) lg[l][e] = s;
  }
  __syncthreads();
  if (t < 8) {
    float m = fmaxf(fmaxf(lg[t][0], lg[t][1]), fmaxf(lg[t][2], lg[t][3]));
    float e0 = expf(lg[t][0] - m), e1 = expf(lg[t][1] - m);
    float e2 = expf(lg[t][2] - m), e3 = expf(lg[t][3] - m);
    float inv = 1.0f / (e0 + e1 + e2 + e3);
    gs[t][0] = e0 * inv; gs[t][1] = e1 * inv;
    gs[t][2] = e2 * inv; gs[t][3] = e3 * inv;
  }
  __syncthreads();
  if (t < 4) {
    float g = 0;
#pragma unroll
    for (int l = 0; l < 8; ++l) g += gs[l][t];
    gsum[b * 4 + t] = g;
  }
#pragma unroll
  for (int rep = 0; rep < 4; ++rep) {
    int d = t + rep * 256;
    float a0 = 0, a1 = 0, a2 = 0, a3 = 0;
#pragma unroll
    for (int l = 0; l < 8; ++l) {
      float ov = os[l][d];
      a0 += gs[l][0] * ov; a1 += gs[l][1] * ov;
      a2 += gs[l][2] * ov; a3 += gs[l][3] * ov;
    }
    ae[(size_t)0 * 524288 + b * 1024 + d] = f2bf(a0);
    ae[(size_t)1 * 524288 + b * 1024 + d] = f2bf(a1);
    ae[(size_t)2 * 524288 + b * 1024 + d] = f2bf(a2);
    ae[(size_t)3 * 524288 + b * 1024 + d] = f2bf(a3);
  }
}

// ---------------------------------------------------------------------------
// Pooled MoE GEMM (experts folded into K-accumulation)
// ---------------------------------------------------------------------------
__global__ __launch_bounds__(256) void gemm_moe2(
    const ushort* __restrict__ AE, const ushort* __restrict__ Bt4,
    const float* __restrict__ expb, const float* __restrict__ gsum,
    float* __restrict__ out) {
  __shared__ ushort As[64 * 40];
  __shared__ ushort Bs[64 * 40];
  const int bx = blockIdx.x, by = blockIdx.y;
  const int t = threadIdx.x;
  const int wv = t >> 6, lane = t & 63;
  const int wr = (wv >> 1) * 32, wc = (wv & 1) * 32;
  const int srow = t >> 2, sq = t & 3;
  const int la = lane & 15, lk = (lane >> 4) * 8;
  const int sdst = srow * 40 + sq * 8;
  f32x4 acc[2][2];
  const f32x4 z4 = {0.f, 0.f, 0.f, 0.f};
  acc[0][0] = z4; acc[0][1] = z4; acc[1][0] = z4; acc[1][1] = z4;
  for (int e = 0; e < 4; ++e) {
    const ushort* Ag = AE + (size_t)e * 524288 + (size_t)(by * 64 + srow) * 1024 + sq * 8;
    const ushort* Bg = Bt4 + (size_t)e * 1048576 + (size_t)(bx * 64 + srow) * 1024 + sq * 8;
    uint4 ra = *reinterpret_cast<const uint4*>(Ag);
    uint4 rb = *reinterpret_cast<const uint4*>(Bg);
    for (int kt = 0; kt < 1024; kt += 32) {
      __syncthreads();
      *reinterpret_cast<uint4*>(&As[sdst]) = ra;
      *reinterpret_cast<uint4*>(&Bs[sdst]) = rb;
      __syncthreads();
      if (kt + 32 < 1024) {
        ra = *reinterpret_cast<const uint4*>(Ag + kt + 32);
        rb = *reinterpret_cast<const uint4*>(Bg + kt + 32);
      }
      short8v af[2], bfr[2];
#pragma unroll
      for (int i = 0; i < 2; ++i)
        af[i] = *reinterpret_cast<const short8v*>(&As[(wr + i * 16 + la) * 40 + lk]);
#pragma unroll
      for (int j = 0; j < 2; ++j)
        bfr[j] = *reinterpret_cast<const short8v*>(&Bs[(wc + j * 16 + la) * 40 + lk]);
#pragma unroll
      for (int i = 0; i < 2; ++i)
#pragma unroll
        for (int j = 0; j < 2; ++j)
          acc[i][j] = __builtin_amdgcn_mfma_f32_16x16x32_bf16(af[i], bfr[j], acc[i][j], 0, 0, 0);
    }
  }
  const int r0 = by * 64 + wr + (lane >> 4) * 4;
  const int c0 = bx * 64 + wc + la;
#pragma unroll
  for (int i = 0; i < 2; ++i)
#pragma unroll
    for (int q = 0; q < 4; ++q) {
      int r = r0 + i * 16 + q;
      float4 gv = *reinterpret_cast<const float4*>(gsum + r * 4);
#pragma unroll
      for (int j = 0; j < 2; ++j) {
        int c = c0 + j * 16;
        float bias = gv.x * expb[c] + gv.y * expb[1024 + c] +
                     gv.z * expb[2048 + c] + gv.w * expb[3072 + c];
        float s = (acc[i][j][q] + bias) * 0.125f;
        out[(size_t)r * 1024 + c] = 1.0f / (1.0f + expf(-s));
      }
    }
}

// weight transpose + bf16 convert: Bt[n*K+k] = bf16(W[k*N+n])
__global__ __launch_bounds__(256) void k_wt_bt(const float* __restrict__ W,
                                               ushort* __restrict__ Bt, int K, int N) {
  __shared__ float tile[32][33];
  int n0 = blockIdx.x * 32, k0 = blockIdx.y * 32;
  int tx = threadIdx.x & 31, ty = threadIdx.x >> 5;
#pragma unroll
  for (int i = 0; i < 4; ++i)
    tile[ty + 8 * i][tx] = W[(size_t)(k0 + ty + 8 * i) * N + n0 + tx];
  __syncthreads();
#pragma unroll
  for (int i = 0; i < 4; ++i)
    Bt[(size_t)(n0 + ty + 8 * i) * K + k0 + tx] = f2bf(tile[tx][ty + 8 * i]);
}

// batched transpose: W strided by z
__global__ __launch_bounds__(256) void k_wt_bt_s(const float* __restrict__ Wbase,
                                                 ushort* __restrict__ Btbase, int K, int N) {
  __shared__ float tile[32][33];
  const float* W = Wbase + (size_t)blockIdx.z * K * N;
  ushort* Bt = Btbase + (size_t)blockIdx.z * K * N;
  int n0 = blockIdx.x * 32, k0 = blockIdx.y * 32;
  int tx = threadIdx.x & 31, ty = threadIdx.x >> 5;
#pragma unroll
  for (int i = 0; i < 4; ++i)
    tile[ty + 8 * i][tx] = W[(size_t)(k0 + ty + 8 * i) * N + n0 + tx];
  __syncthreads();
#pragma unroll
  for (int i = 0; i < 4; ++i)
    Bt[(size_t)(n0 + ty + 8 * i) * K + k0 + tx] = f2bf(tile[tx][ty + 8 * i]);
}

// batched transpose for 3 separate weight pointers (QKV)
__global__ __launch_bounds__(256) void k_wt_bt3(const float* __restrict__ w0,
                                                const float* __restrict__ w1,
                                                const float* __restrict__ w2,
                                                ushort* __restrict__ Btbase, int K, int N) {
  __shared__ float tile[32][33];
  const float* W = (blockIdx.z == 0) ? w0 : (blockIdx.z == 1) ? w1 : w2;
  ushort* Bt = Btbase + (size_t)blockIdx.z * K * N;
  int n0 = blockIdx.x * 32, k0 = blockIdx.y * 32;
  int tx = threadIdx.x & 31, ty = threadIdx.x >> 5;
#pragma unroll
  for (int i = 0; i < 4; ++i)
    tile[ty + 8 * i][tx] = W[(size_t)(k0 + ty + 8 * i) * N + n0 + tx];
  __syncthreads();
#pragma unroll
  for (int i = 0; i < 4; ++i)
    Bt[(size_t)(n0 + ty + 8 * i) * K + k0 + tx] = f2bf(tile[tx][ty + 8 * i]);
}

// ---------------------------------------------------------------------------
// Fused S post-process: SB bf16 write + MSG build + emb_sum partial.
// ---------------------------------------------------------------------------
__global__ __launch_bounds__(256) void k_post_s(
    const float* __restrict__ s1, const float* __restrict__ s2,
    const float* __restrict__ relation, const int* __restrict__ etype,
    ushort* __restrict__ sb, ushort* __restrict__ msg, float* __restrict__ emb_out) {
  __shared__ float sh[256];
  float part = 0.f;
  for (int idx = blockIdx.x * 256 + threadIdx.x; idx < 1048576; idx += 128 * 256) {
    float vs = (idx < 524288) ? s1[idx] : s2[idx - 524288];
    sb[idx] = f2bf(vs);
    int i = idx >> 8, j = idx & 255;
    int et = etype[i];
    float sign = (et >= cNR) ? -1.0f : 1.0f;
    float r = relation[(size_t)(et % cNR) * 256 + j];
    float s = (j < 128) ? s1[(size_t)i * 128 + j] : s2[(size_t)i * 128 + j - 128];
    msg[idx] = f2bf(fmaxf(s + r * sign, 0.0f));
    part += s * s + r * r;
  }
  float tot = blockReduce256(part, sh, threadIdx.x);
  if (threadIdx.x == 0) atomAdd(emb_out, tot);
}

// in-place bf16 row normalize (wave reduction, 1 sync)
__global__ __launch_bounds__(128) void rownorm_bf2(ushort* __restrict__ w) {
  __shared__ float sh[2];
  int i = blockIdx.x, tid = threadIdx.x;
  float v = bf2f(w[(size_t)i * cD + tid]);
  float ss = v * v;
#pragma unroll
  for (int off = 32; off > 0; off >>= 1) ss += __shfl_xor(ss, off);
  if ((tid & 63) == 0) sh[tid >> 6] = ss;
  __syncthreads();
  float n = fmaxf(sqrtf(sh[0] + sh[1]), 1e-12f);
  w[(size_t)i * cD + tid] = f2bf(v / n);
}

// fused-QKV attention: qkv [4096][3072], o [4096][1024] bf16
__global__ __launch_bounds__(64) void mha_attn(
    const ushort* __restrict__ qkv, ushort* __restrict__ o) {
  __shared__ float qs[8][132], ks[8][132], vs[8][132];
  __shared__ float att[8][8];
  int bh = blockIdx.x;
  int b = bh >> 3, h = bh & 7;
  int tid = threadIdx.x;
  for (int u = tid; u < 256; u += 64) {
    int l = u >> 5;
    int d4 = (u & 31) * 4;
    size_t base = (size_t)(b * 8 + l) * 3072 + h * 128 + d4;
    ushort4 qv = *reinterpret_cast<const ushort4*>(qkv + base);
    ushort4 kv = *reinterpret_cast<const ushort4*>(qkv + base + 1024);
    ushort4 vv = *reinterpret_cast<const ushort4*>(qkv + base + 2048);
    qs[l][d4] = bf2f(qv.x); qs[l][d4 + 1] = bf2f(qv.y);
    qs[l][d4 + 2] = bf2f(qv.z); qs[l][d4 + 3] = bf2f(qv.w);
    ks[l][d4] = bf2f(kv.x); ks[l][d4 + 1] = bf2f(kv.y);
    ks[l][d4 + 2] = bf2f(kv.z); ks[l][d4 + 3] = bf2f(kv.w);
    vs[l][d4] = bf2f(vv.x); vs[l][d4 + 1] = bf2f(vv.y);
    vs[l][d4 + 2] = bf2f(vv.z); vs[l][d4 + 3] = bf2f(vv.w);
  }
  __syncthreads();
  int l = tid >> 3, m = tid & 7;
  const float4* qp = reinterpret_cast<const float4*>(&qs[l][0]);
  const float4* kp = reinterpret_cast<const float4*>(&ks[m][0]);
  float s = 0;
#pragma unroll
  for (int d4 = 0; d4 < 32; ++d4) {
    float4 a = qp[d4], bb = kp[d4];
    s += a.x * bb.x + a.y * bb.y + a.z * bb.z + a.w * bb.w;
  }
  s *= 0.08838834764831845f;
  float mx = s;
  for (int off = 1; off < 8; off <<= 1) mx = fmaxf(mx, __shfl_xor(mx, off, 8));
  float p = expf(s - mx);
  float sum = p;
  for (int off = 1; off < 8; off <<= 1) sum += __shfl_xor(sum, off, 8);
  att[l][m] = p / sum;
  __syncthreads();
  for (int u = tid; u < 1024; u += 64) {
    int ll = u >> 7, d = u & 127;
    float acc = 0;
#pragma unroll
    for (int mm = 0; mm < 8; ++mm) acc += att[ll][mm] * vs[mm][d];
    o[(size_t)(b * 8 + ll) * 1024 + h * 128 + d] = f2bf(acc);
  }
}

__global__ void finalize_k(const float* __restrict__ scal, float* __restrict__ out_aux) {
  float cl = scal[0] * (1.0f / cNSRC);
  float emb = cDECAY * 0.5f * scal[1] * (1.0f / cNSRC);
  out_aux[0] = cCLW * cl + emb;
}

// ---------------------------------------------------------------------------
// Launch
// ---------------------------------------------------------------------------
extern "C" void kernel_launch(void* const* d_in, const int* in_sizes, int n_in,
                              void* d_out, int out_size, void* d_ws, size_t ws_size,
                              hipStream_t stream) {
  (void)in_sizes; (void)n_in; (void)out_size; (void)ws_size;
  const float* entity   = (const float*)d_in[0];
  const float* type_e   = (const float*)d_in[1];
  const float* cluster  = (const float*)d_in[2];
  const float* relation = (const float*)d_in[3];
  const float* ln_g  = (const float*)d_in[4];
  const float* ln_b  = (const float*)d_in[5];
  const float* cl_w1 = (const float*)d_in[6];
  const float* cl_b1 = (const float*)d_in[7];
  const float* cl_w2 = (const float*)d_in[8];
  const float* cl_b2 = (const float*)d_in[9];
  const float* fc_w  = (const float*)d_in[10];
  const float* fc_b  = (const float*)d_in[11];
  const float* wq = (const float*)d_in[12];
  const float* bq = (const float*)d_in[13];
  const float* wk = (const float*)d_in[14];
  const float* bk = (const float*)d_in[15];
  const float* wv = (const float*)d_in[16];
  const float* bv = (const float*)d_in[17];
  const float* wo = (const float*)d_in[18];
  const float* bo = (const float*)d_in[19];
  const float* gate_w = (const float*)d_in[20];
  const float* exp_w  = (const float*)d_in[21];
  const float* exp_b  = (const float*)d_in[22];
  const float* e2t_val = (const float*)d_in[23];
  const float* t2c_val = (const float*)d_in[24];
  const float* e2c_val = (const float*)d_in[25];
  const int* e2t_row = (const int*)d_in[26];
  const int* e2t_col = (const int*)d_in[27];
  const int* t2c_row = (const int*)d_in[28];
  const int* t2c_col = (const int*)d_in[29];
  const int* e2c_row = (const int*)d_in[30];
  const int* e2c_col = (const int*)d_in[31];
  const int* src_ids = (const int*)d_in[32];
  const int* etype   = (const int*)d_in[33];

  float* ws = (float*)d_ws;
  float* S1 = ws + F_S1;
  float* S2 = ws + F_S2;
  ushort* Wbf = (ushort*)(ws + F_PT);
  ushort* P1bf = (ushort*)(ws + F_Z1);
  ushort* SBbf = (ushort*)(ws + F_Z2);
  ushort* MSGbf = (ushort*)(ws + F_MSG);
  float* GSUM = ws + F_GATE;
  float* SCAL = ws + F_SCAL;
  float* RS   = ws + F_RS;
  float* D11  = ws + F_D11;
  float* D12  = ws + F_D12;
  float* D22  = ws + F_D22;
  ushort* X1F = (ushort*)(ws + G_X1F);
  ushort* X2C = (ushort*)(ws + G_X2C);
  int*   MARK = (int*)(ws + G_X2C);     // aliased: dead before X2C written
  int*   SLOT = (int*)(ws + G_SLOT);
  int*   REP  = (int*)(ws + G_REP);
  int*   RP   = (int*)(ws + G_RP);
  int*   FILL = (int*)(ws + G_FILL);
  int*   COLS = (int*)(ws + G_COLS);
  float* VALS = ws + G_VALS;
  ushort* X1T = (ushort*)(ws + G_X1T);
  ushort* X2T = (ushort*)(ws + G_X2T);
  int*   BSUM = (int*)(ws + G_BSUM);
  ushort* EBF = (ushort*)(ws + G_EBF);
  ushort* TBF = (ushort*)(ws + G_TBF);
  ushort* CBF = (ushort*)(ws + G_CBF);
  ushort* PB   = (ushort*)(ws + A_U0);
  ushort* AE   = (ushort*)(ws + A_U0);
  ushort* QKV  = (ushort*)(ws + A_U1);
  ushort* OB   = (ushort*)(ws + A_U1);
  ushort* WBT  = (ushort*)(ws + A_WBT);
  float* BQKV2 = ws + F_GATE + 8192;    // separate from RS (gram writes RS concurrently)

  hipMemsetAsync(SCAL, 0, 2 * sizeof(float), stream);
  hipMemsetAsync(RS, 0, (16384 + 3 * 4096) * sizeof(float), stream);

  // bf16 embedding tables (once)
  k_to_bf<<<2048, 256, 0, stream>>>(entity, EBF, cNE * cD / 4);
  k_to_bf<<<128, 256, 0, stream>>>(type_e, TBF, cNT * cD / 4);
  k_to_bf<<<16, 256, 0, stream>>>(cluster, CBF, cNC * cD / 4);

  // masked GCN
  auto run_gcn_masked = [&](const int* row, const int* col, const float* val, int nnz, int nn,
                            const float* ea_f, const float* eb_f,
                            const ushort* ea_b, const ushort* eb_b, int na, int mode,
                            float* dst) {
    int nb = (nn + 255) / 256;
    int gEdge = (nnz + 255) / 256;
    k_init3<<<nb, 256, 0, stream>>>(SLOT, MARK, FILL, nn);
    k_slot_mark<<<16, 256, 0, stream>>>(src_ids, SLOT, MARK, mode);
    k_mark_edges<<<gEdge, 256, 0, stream>>>(row, col, nnz, SLOT, MARK);
    k_hist<<<gEdge, 256, 0, stream>>>(row, nnz, MARK, FILL);
    k_scan_block<<<nb, 256, 0, stream>>>(FILL, nn, RP, BSUM);
    k_bsum_scan<<<1, 512, 0, stream>>>(BSUM, nb, RP, nn);
    k_scan_add<<<nb, 256, 0, stream>>>(RP, BSUM, nn, FILL);
    k_fill<<<gEdge, 256, 0, stream>>>(row, col, val, nnz, MARK, FILL, COLS, VALS);
    k_rep<<<16, 256, 0, stream>>>(src_ids, SLOT, mode, REP);
    k_gather<<<(nn + 3) / 4, 256, 0, stream>>>(RP, COLS, VALS, ea_b, eb_b, na, nn, MARK, X1F);
    k_gather_slot<<<cNSRC / 4, 256, 0, stream>>>(RP, COLS, VALS, X1F, REP, X2C);
    gather_ln<<<cNSRC, 128, 0, stream>>>(src_ids, mode, ea_f, eb_f, na, X1F, X2C, SLOT,
                                         ln_g, ln_b, dst);
  };

  run_gcn_masked(e2t_row, e2t_col, e2t_val, cNNZ_E2T, cNN_E2T,
                 entity, type_e, EBF, TBF, cNE, 0, S1);
  run_gcn_masked(e2c_row, e2c_col, e2c_val, cNNZ_E2C, cNN_E2C,
                 entity, cluster, EBF, CBF, cNE, 3, S2);

  // ---- t2c: tiny, both layers full ----
  {
    int nn = cNN_T2C, nb = (nn + 255) / 256, gEdge = (cNNZ_T2C + 255) / 256;
    hipMemsetAsync(FILL, 0, (size_t)nn * sizeof(int), stream);
    k_hist<<<gEdge, 256, 0, stream>>>(t2c_row, cNNZ_T2C, nullptr, FILL);
    k_scan_block<<<nb, 256, 0, stream>>>(FILL, nn, RP, BSUM);
    k_bsum_scan<<<1, 512, 0, stream>>>(BSUM, nb, RP, nn);
    k_scan_add<<<nb, 256, 0, stream>>>(RP, BSUM, nn, FILL);
    k_fill<<<gEdge, 256, 0, stream>>>(t2c_row, t2c_col, t2c_val, cNNZ_T2C, nullptr,
                                      FILL, COLS, VALS);
    k_gather<<<(nn + 3) / 4, 256, 0, stream>>>(RP, COLS, VALS, TBF, CBF, cNT,
                                               nn, nullptr, X1T);
    k_gather_bf<<<(nn + 3) / 4, 256, 0, stream>>>(RP, COLS, VALS, X1T, nn, X2T);
    gather_ln<<<cNSRC, 128, 0, stream>>>(src_ids, 1, type_e, cluster, cNT, X1T, X2T, nullptr,
                                         ln_g, ln_b, S1);
    gather_ln<<<cNSRC, 128, 0, stream>>>(src_ids, 2, type_e, cluster, cNT, X1T, X2T, nullptr,
                                         ln_g, ln_b, S2);
  }

  // ================= fused S post-process (SB + MSG + emb_sum) =================
  k_post_s<<<128, 256, 0, stream>>>(S1, S2, relation, etype, SBbf, MSGbf, SCAL + 1);

  // ================= contrastive projections =================
  ushort* W1T = WBT;
  ushort* W2T = WBT + 16384;
  k_wt_bt<<<dim3(4, 4), 256, 0, stream>>>(cl_w1, W1T, cD, cD);
  k_wt_bt<<<dim3(4, 4), 256, 0, stream>>>(cl_w2, W2T, cD, cD);
  gemm_bf<<<dim3(1, 64), 256, 0, stream>>>(SBbf, W1T, cD, cD, cl_b1, P1bf, 1);
  gemm_bf<<<dim3(1, 64), 256, 0, stream>>>(P1bf, W2T, cD, cD, cl_b2, Wbf, 0);
  rownorm_bf2<<<2 * cNSRC, 128, 0, stream>>>(Wbf);

  // ================= predict =================
  k_wt_bt<<<dim3(cT / 32, 256 / 32), 256, 0, stream>>>(fc_w, WBT, 256, cT);
  gemm_bf<<<dim3(cT / 128, cNSRC / 128), 256, 0, stream>>>(MSGbf, WBT, cT, 256, fc_b, PB, 0);

  // ================= QKV weight prep, then fused (interleaved) gram+QKV ======
  k_wt_bt3<<<dim3(32, 32, 3), 256, 0, stream>>>(wq, wk, wv, WBT, cT, cT);
  k_pack_bias<<<12, 256, 0, stream>>>(bq, bk, bv, BQKV2);
  k_gram_qkv<<<2848, 256, 0, stream>>>(Wbf, RS, D11, D12, D22,
                                       PB, WBT, BQKV2, QKV);
  cl_row<<<16, 256, 0, stream>>>(RS, D11, D12, D22, SCAL);

  // ================= MHA tail =================
  mha_attn<<<cB * 8, 64, 0, stream>>>(QKV, PB);
  k_wt_bt<<<dim3(32, 32), 256, 0, stream>>>(wo, WBT, cT, cT);
  gemm_bf<<<dim3(cT / 128, cNSRC / 128), 256, 0, stream>>>(PB, WBT, cT, cT, bo, OB, 0);

  // ================= pooled MoE =================
  k_gate_pool<<<cB, 256, 0, stream>>>(OB, gate_w, AE, GSUM);
  k_wt_bt_s<<<dim3(32, 32, 4), 256, 0, stream>>>(exp_w, WBT, cT, cT);
  gemm_moe2<<<dim3(16, 8), 256, 0, stream>>>(AE, WBT, exp_b, GSUM, (float*)d_out);

  finalize_k<<<1, 1, 0, stream>>>(SCAL, (float*)d_out + (size_t)cB * cT);
}

// Round 14
// 528.495 us; speedup vs baseline: 1.0510x; 1.0510x over previous
//
#include <hip/hip_runtime.h>
#include <hip/hip_bf16.h>
#include <cmath>

// ---------------------------------------------------------------------------
// Problem constants (fixed shapes)
// ---------------------------------------------------------------------------
constexpr int cNE = 100000, cNT = 1024, cNC = 128, cD = 128, cNR = 500;
constexpr int cB = 512, cNSRC = 4096, cT = 1024, cE = 4;
constexpr int cNNZ_E2T = 1000000, cNNZ_T2C = 50000, cNNZ_E2C = 500000;
constexpr float cDECAY = 1e-4f, cCLW = 0.1f;
constexpr int cNN_E2T = cNE + cNT;     // 101024
constexpr int cNN_E2C = cNE + cNC;     // 100128
constexpr int cNN_T2C = cNT + cNC;     // 1152

// ---------------------------------------------------------------------------
// Workspace layout (FLOAT units)
// ---------------------------------------------------------------------------
constexpr size_t F_S1   = 0;                          // f32 4096x128
constexpr size_t F_S2   = F_S1 + 524288;
constexpr size_t F_PT   = F_S2 + 524288;              // bf16 W [8192][128]
constexpr size_t F_Z1   = F_PT + 524288;              // bf16 P1
constexpr size_t F_Z2   = F_Z1 + 524288;              // bf16 SB
constexpr size_t F_MSG  = F_Z2 + 524288;              // bf16 4096x256
constexpr size_t F_GATE = F_MSG + 524288;             // f32 GSUM [512][4]
constexpr size_t F_SCAL = F_GATE + 16384;
constexpr size_t F_RS   = F_SCAL + 64;                // f32 [2][8192]; later bias_qkv
constexpr size_t F_D11  = F_RS + 16384;
constexpr size_t F_D12  = F_D11 + 4096;
constexpr size_t F_D22  = F_D12 + 4096;
constexpr size_t F_U    = F_D22 + 4096;               // union base
// --- GCN phase ---
constexpr size_t G_X1F  = F_U;                        // ushort[101024*128]
constexpr size_t G_X2C  = G_X1F + 6465536;            // ushort[4096*128] (also MARK)
constexpr size_t G_SLOT = G_X2C + 262144;
constexpr size_t G_REP  = G_SLOT + 101376;
constexpr size_t G_RP   = G_REP + 4096;
constexpr size_t G_FILL = G_RP + 101376;
constexpr size_t G_COLS = G_FILL + 101376;
constexpr size_t G_VALS = G_COLS + 1000000;
constexpr size_t G_X1T  = G_VALS + 1000000;
constexpr size_t G_X2T  = G_X1T + 73728;
constexpr size_t G_BSUM = G_X2T + 73728;              // int[512]
constexpr size_t G_EBF  = G_BSUM + 512;               // ushort[100000*128]
constexpr size_t G_TBF  = G_EBF + 3200000;
constexpr size_t G_CBF  = G_TBF + 65536;
// --- activation phase ---
constexpr size_t A_U0  = F_U;
constexpr size_t A_U1  = F_U + 2097152;
constexpr size_t A_WBT = F_U + 4 * 2097152;

typedef __attribute__((ext_vector_type(8))) short short8v;
typedef __attribute__((ext_vector_type(4))) float f32x4;

// ---------------------------------------------------------------------------
// Helpers
// ---------------------------------------------------------------------------
__device__ __forceinline__ void atomAdd(float* p, float v) {
  __hip_atomic_fetch_add(p, v, __ATOMIC_RELAXED, __HIP_MEMORY_SCOPE_AGENT);
}
__device__ __forceinline__ ushort f2bf(float f) {
  __hip_bfloat16 h = __float2bfloat16(f);
  return *reinterpret_cast<ushort*>(&h);
}
__device__ __forceinline__ float bf2f(ushort u) {
  __hip_bfloat16 h; *reinterpret_cast<ushort*>(&h) = u;
  return __bfloat162float(h);
}

__device__ __forceinline__ int mapNode(int mode, int id) {
  switch (mode) {
    case 0:  return (id < cNE + cNT) ? id : -1;
    case 1:  return (id >= cNE + cNT) ? (id - cNE) : -1;
    case 2:  return (id >= cNE && id < cNE + cNT) ? (id - cNE) : -1;
    default: return (id < cNE) ? id
                   : ((id >= cNE + cNT) ? (id - cNT) : -1);
  }
}

__device__ __forceinline__ float blockReduce256(float v, float* sh, int tid) {
  sh[tid] = v; __syncthreads();
  for (int s = 128; s > 0; s >>= 1) {
    if (tid < s) sh[tid] += sh[tid + s];
    __syncthreads();
  }
  float r = sh[0]; __syncthreads();
  return r;
}

// ---------------------------------------------------------------------------
// f32 -> bf16 table conversion (grid-stride over quads)
// ---------------------------------------------------------------------------
__global__ __launch_bounds__(256) void k_to_bf(const float* __restrict__ src,
                                               ushort* __restrict__ dst, int nq) {
  for (int q = blockIdx.x * 256 + threadIdx.x; q < nq; q += gridDim.x * 256) {
    float4 v = *reinterpret_cast<const float4*>(src + (size_t)q * 4);
    ushort4 o;
    o.x = f2bf(v.x); o.y = f2bf(v.y); o.z = f2bf(v.z); o.w = f2bf(v.w);
    *reinterpret_cast<ushort4*>(dst + (size_t)q * 4) = o;
  }
}

// pack bq|bk|bv into one 3072-float buffer
__global__ __launch_bounds__(256) void k_pack_bias(const float* __restrict__ b0,
                                                   const float* __restrict__ b1,
                                                   const float* __restrict__ b2,
                                                   float* __restrict__ dst) {
  int i = blockIdx.x * 256 + threadIdx.x;   // 3072 total
  float v = (i < 1024) ? b0[i] : (i < 2048) ? b1[i - 1024] : b2[i - 2048];
  dst[i] = v;
}

// ---------------------------------------------------------------------------
// init + mask + CSR build
// ---------------------------------------------------------------------------
__global__ __launch_bounds__(256) void k_init3(int* __restrict__ slot, int* __restrict__ mark,
                                               int* __restrict__ fill, int n) {
  int i = blockIdx.x * 256 + threadIdx.x;
  if (i < n) { slot[i] = 0x7f7f7f7f; mark[i] = 0; fill[i] = 0; }
}

__global__ __launch_bounds__(256) void k_slot_mark(const int* __restrict__ ids,
                                                   int* __restrict__ slot,
                                                   int* __restrict__ mark, int mode) {
  int i = blockIdx.x * 256 + threadIdx.x;
  if (i >= cNSRC) return;
  int node = mapNode(mode, ids[i]);
  if (node >= 0) { atomicMin(&slot[node], i); mark[node] = 1; }
}

__global__ __launch_bounds__(256) void k_mark_edges(const int* __restrict__ row,
                                                    const int* __restrict__ col, int nnz,
                                                    const int* __restrict__ slot,
                                                    int* __restrict__ mark) {
  int e = blockIdx.x * 256 + threadIdx.x;
  if (e >= nnz) return;
  int r = row[e];
  if (slot[r] < cNSRC) mark[col[e]] = 1;
}

__global__ __launch_bounds__(256) void k_hist(const int* __restrict__ row, int nnz,
                                              const int* __restrict__ mark,
                                              int* __restrict__ cnt) {
  int e = blockIdx.x * 256 + threadIdx.x;
  if (e >= nnz) return;
  int r = row[e];
  if (mark && !mark[r]) return;
  atomicAdd(&cnt[r], 1);
}

__global__ __launch_bounds__(256) void k_scan_block(const int* __restrict__ cnt, int n,
                                                    int* __restrict__ excl, int* __restrict__ bsum) {
  __shared__ int sh[256];
  int tid = threadIdx.x;
  int i = blockIdx.x * 256 + tid;
  int v = (i < n) ? cnt[i] : 0;
  sh[tid] = v; __syncthreads();
  for (int off = 1; off < 256; off <<= 1) {
    int t = (tid >= off) ? sh[tid - off] : 0;
    __syncthreads();
    sh[tid] += t;
    __syncthreads();
  }
  if (i < n) excl[i] = sh[tid] - v;
  if (tid == 255) bsum[blockIdx.x] = sh[255];
}

__global__ __launch_bounds__(512) void k_bsum_scan(int* __restrict__ bsum, int nb,
                                                   int* __restrict__ rowptr, int n) {
  __shared__ int sh[512];
  int tid = threadIdx.x;
  int v = (tid < nb) ? bsum[tid] : 0;
  sh[tid] = v; __syncthreads();
  for (int off = 1; off < 512; off <<= 1) {
    int t = (tid >= off) ? sh[tid - off] : 0;
    __syncthreads();
    sh[tid] += t;
    __syncthreads();
  }
  if (tid < nb) bsum[tid] = sh[tid] - v;
  if (tid == 511) rowptr[n] = sh[511];
}

__global__ __launch_bounds__(256) void k_scan_add(int* __restrict__ rowptr,
                                                  const int* __restrict__ bsum, int n,
                                                  int* __restrict__ fill) {
  int i = blockIdx.x * 256 + threadIdx.x;
  if (i < n) {
    int r = rowptr[i] + bsum[blockIdx.x];
    rowptr[i] = r;
    fill[i] = r;
  }
}

__global__ __launch_bounds__(256) void k_fill(const int* __restrict__ row,
                                              const int* __restrict__ col,
                                              const float* __restrict__ val, int nnz,
                                              const int* __restrict__ mark,
                                              int* __restrict__ fill,
                                              int* __restrict__ cols, float* __restrict__ vals) {
  int e = blockIdx.x * 256 + threadIdx.x;
  if (e >= nnz) return;
  int r = row[e];
  if (mark && !mark[r]) return;
  int pos = atomicAdd(&fill[r], 1);
  cols[pos] = col[e];
  vals[pos] = val[e];
}

// wave-per-row gather, bf16 tables in -> bf16 out (4-wide unrolled)
__global__ __launch_bounds__(256) void k_gather(
    const int* __restrict__ rowptr, const int* __restrict__ cols, const float* __restrict__ vals,
    const ushort* __restrict__ ea, const ushort* __restrict__ eb, int na,
    int nrows, const int* __restrict__ mark, ushort* __restrict__ out) {
  int r = blockIdx.x * 4 + (threadIdx.x >> 6);
  if (r >= nrows) return;
  if (mark && !mark[r]) return;
  int lane = threadIdx.x & 63;
  int p0 = rowptr[r], p1 = rowptr[r + 1];
  float ax = 0.f, ay = 0.f;
  int p = p0;
  for (; p + 4 <= p1; p += 4) {
    int c0 = cols[p], c1 = cols[p + 1], c2 = cols[p + 2], c3 = cols[p + 3];
    float v0 = vals[p], v1 = vals[p + 1], v2 = vals[p + 2], v3 = vals[p + 3];
    const ushort* s0 = (c0 < na) ? (ea + (size_t)c0 * cD) : (eb + (size_t)(c0 - na) * cD);
    const ushort* s1 = (c1 < na) ? (ea + (size_t)c1 * cD) : (eb + (size_t)(c1 - na) * cD);
    const ushort* s2 = (c2 < na) ? (ea + (size_t)c2 * cD) : (eb + (size_t)(c2 - na) * cD);
    const ushort* s3 = (c3 < na) ? (ea + (size_t)c3 * cD) : (eb + (size_t)(c3 - na) * cD);
    ushort2 x0 = *reinterpret_cast<const ushort2*>(s0 + lane * 2);
    ushort2 x1 = *reinterpret_cast<const ushort2*>(s1 + lane * 2);
    ushort2 x2 = *reinterpret_cast<const ushort2*>(s2 + lane * 2);
    ushort2 x3 = *reinterpret_cast<const ushort2*>(s3 + lane * 2);
    ax += v0 * bf2f(x0.x) + v1 * bf2f(x1.x) + v2 * bf2f(x2.x) + v3 * bf2f(x3.x);
    ay += v0 * bf2f(x0.y) + v1 * bf2f(x1.y) + v2 * bf2f(x2.y) + v3 * bf2f(x3.y);
  }
  for (; p < p1; ++p) {
    int c = cols[p];
    float v = vals[p];
    const ushort* s = (c < na) ? (ea + (size_t)c * cD) : (eb + (size_t)(c - na) * cD);
    ushort2 x = *reinterpret_cast<const ushort2*>(s + lane * 2);
    ax += v * bf2f(x.x); ay += v * bf2f(x.y);
  }
  ushort2 o; o.x = f2bf(ax); o.y = f2bf(ay);
  *reinterpret_cast<ushort2*>(out + (size_t)r * cD + lane * 2) = o;
}

__global__ __launch_bounds__(256) void k_rep(const int* __restrict__ ids,
                                             const int* __restrict__ slot, int mode,
                                             int* __restrict__ rep) {
  int i = blockIdx.x * 256 + threadIdx.x;
  if (i >= cNSRC) return;
  int node = mapNode(mode, ids[i]);
  rep[i] = (node >= 0 && slot[node] == i) ? node : -1;
}

// layer-2 gather at representative slots (4-wide unrolled)
__global__ __launch_bounds__(256) void k_gather_slot(
    const int* __restrict__ rowptr, const int* __restrict__ cols, const float* __restrict__ vals,
    const ushort* __restrict__ x1, const int* __restrict__ rep,
    ushort* __restrict__ outc) {
  int i = blockIdx.x * 4 + (threadIdx.x >> 6);
  if (i >= cNSRC) return;
  int r = rep[i];
  if (r < 0) return;
  int lane = threadIdx.x & 63;
  int p0 = rowptr[r], p1 = rowptr[r + 1];
  float ax = 0.f, ay = 0.f;
  int p = p0;
  for (; p + 4 <= p1; p += 4) {
    int c0 = cols[p], c1 = cols[p + 1], c2 = cols[p + 2], c3 = cols[p + 3];
    float v0 = vals[p], v1 = vals[p + 1], v2 = vals[p + 2], v3 = vals[p + 3];
    ushort2 x0 = *reinterpret_cast<const ushort2*>(x1 + (size_t)c0 * cD + lane * 2);
    ushort2 x1v = *reinterpret_cast<const ushort2*>(x1 + (size_t)c1 * cD + lane * 2);
    ushort2 x2 = *reinterpret_cast<const ushort2*>(x1 + (size_t)c2 * cD + lane * 2);
    ushort2 x3 = *reinterpret_cast<const ushort2*>(x1 + (size_t)c3 * cD + lane * 2);
    ax += v0 * bf2f(x0.x) + v1 * bf2f(x1v.x) + v2 * bf2f(x2.x) + v3 * bf2f(x3.x);
    ay += v0 * bf2f(x0.y) + v1 * bf2f(x1v.y) + v2 * bf2f(x2.y) + v3 * bf2f(x3.y);
  }
  for (; p < p1; ++p) {
    int c = cols[p];
    float v = vals[p];
    ushort2 x = *reinterpret_cast<const ushort2*>(x1 + (size_t)c * cD + lane * 2);
    ax += v * bf2f(x.x); ay += v * bf2f(x.y);
  }
  ushort2 o; o.x = f2bf(ax); o.y = f2bf(ay);
  *reinterpret_cast<ushort2*>(outc + (size_t)i * cD + lane * 2) = o;
}

// full-row gather, bf16 in -> bf16 out (t2c layer 2)
__global__ __launch_bounds__(256) void k_gather_bf(
    const int* __restrict__ rowptr, const int* __restrict__ cols, const float* __restrict__ vals,
    const ushort* __restrict__ x1, int nrows, ushort* __restrict__ out) {
  int r = blockIdx.x * 4 + (threadIdx.x >> 6);
  if (r >= nrows) return;
  int lane = threadIdx.x & 63;
  int p0 = rowptr[r], p1 = rowptr[r + 1];
  float ax = 0.f, ay = 0.f;
  for (int p = p0; p < p1; ++p) {
    int c = cols[p];
    float v = vals[p];
    ushort2 x = *reinterpret_cast<const ushort2*>(x1 + (size_t)c * cD + lane * 2);
    ax += v * bf2f(x.x); ay += v * bf2f(x.y);
  }
  ushort2 o; o.x = f2bf(ax); o.y = f2bf(ay);
  *reinterpret_cast<ushort2*>(out + (size_t)r * cD + lane * 2) = o;
}

// (x0 + x1 + x2)/3 at gathered rows -> LayerNorm -> dst (x1,x2 bf16)
__global__ __launch_bounds__(128) void gather_ln(
    const int* __restrict__ ids, int mode,
    const float* __restrict__ ea, const float* __restrict__ eb, int na,
    const ushort* __restrict__ x1, const ushort* __restrict__ x2, const int* __restrict__ slot,
    const float* __restrict__ g, const float* __restrict__ bia, float* __restrict__ dst) {
  __shared__ float shx[2], shy[2];
  int i = blockIdx.x;
  int tid = threadIdx.x;
  int id = ids[i];
  int node = mapNode(mode, id);
  if (node < 0) return;
  const float* x0 = (node < na) ? (ea + (size_t)node * cD) : (eb + (size_t)(node - na) * cD);
  int xi2 = slot ? slot[node] : node;
  float a = (x0[tid] + bf2f(x1[(size_t)node * cD + tid]) + bf2f(x2[(size_t)xi2 * cD + tid]))
            * (1.0f / 3.0f);
  float sx = a, sy = a * a;
#pragma unroll
  for (int off = 32; off > 0; off >>= 1) {
    sx += __shfl_xor(sx, off);
    sy += __shfl_xor(sy, off);
  }
  if ((tid & 63) == 0) { shx[tid >> 6] = sx; shy[tid >> 6] = sy; }
  __syncthreads();
  float s  = shx[0] + shx[1];
  float ss = shy[0] + shy[1];
  float mu = s * (1.0f / 128.0f);
  float var = ss * (1.0f / 128.0f) - mu * mu;
  float y = (a - mu) * rsqrtf(var + 1e-5f) * g[tid] + bia[tid];
  dst[(size_t)i * cD + tid] = y;
}

// ---------------------------------------------------------------------------
// bf16 MFMA GEMM: C[M,N] = A[M,K] @ Bt[N,K]^T, 128x128 tile, 4 waves
// ---------------------------------------------------------------------------
__global__ __launch_bounds__(256) void gemm_bf(
    const ushort* __restrict__ A, const ushort* __restrict__ Bt,
    int N, int K, const float* __restrict__ bias, ushort* __restrict__ Cbf, int epi) {
  __shared__ ushort As[128 * 40];
  __shared__ ushort Bs[128 * 40];
  const int bx = blockIdx.x, by = blockIdx.y;
  const int t = threadIdx.x;
  const int wv = t >> 6, lane = t & 63;
  const int wr = (wv >> 1) * 64, wc = (wv & 1) * 64;
  const int srow = t >> 1, shalf = t & 1;
  const ushort* Ag = A + (size_t)(by * 128 + srow) * K + shalf * 16;
  const ushort* Bg = Bt + (size_t)(bx * 128 + srow) * K + shalf * 16;
  uint4 ra0 = *reinterpret_cast<const uint4*>(Ag);
  uint4 ra1 = *reinterpret_cast<const uint4*>(Ag + 8);
  uint4 rb0 = *reinterpret_cast<const uint4*>(Bg);
  uint4 rb1 = *reinterpret_cast<const uint4*>(Bg + 8);
  f32x4 acc[4][4];
  const f32x4 z4 = {0.f, 0.f, 0.f, 0.f};
#pragma unroll
  for (int i = 0; i < 4; ++i)
#pragma unroll
    for (int j = 0; j < 4; ++j) acc[i][j] = z4;
  const int la = lane & 15, lk = (lane >> 4) * 8;
  const int sdst = srow * 40 + shalf * 16;
  for (int kt = 0; kt < K; kt += 32) {
    __syncthreads();
    *reinterpret_cast<uint4*>(&As[sdst])     = ra0;
    *reinterpret_cast<uint4*>(&As[sdst + 8]) = ra1;
    *reinterpret_cast<uint4*>(&Bs[sdst])     = rb0;
    *reinterpret_cast<uint4*>(&Bs[sdst + 8]) = rb1;
    __syncthreads();
    if (kt + 32 < K) {
      ra0 = *reinterpret_cast<const uint4*>(Ag + kt + 32);
      ra1 = *reinterpret_cast<const uint4*>(Ag + kt + 40);
      rb0 = *reinterpret_cast<const uint4*>(Bg + kt + 32);
      rb1 = *reinterpret_cast<const uint4*>(Bg + kt + 40);
    }
    short8v af[4], bfr[4];
#pragma unroll
    for (int i = 0; i < 4; ++i)
      af[i] = *reinterpret_cast<const short8v*>(&As[(wr + i * 16 + la) * 40 + lk]);
#pragma unroll
    for (int j = 0; j < 4; ++j)
      bfr[j] = *reinterpret_cast<const short8v*>(&Bs[(wc + j * 16 + la) * 40 + lk]);
#pragma unroll
    for (int i = 0; i < 4; ++i)
#pragma unroll
      for (int j = 0; j < 4; ++j)
        acc[i][j] = __builtin_amdgcn_mfma_f32_16x16x32_bf16(af[i], bfr[j], acc[i][j], 0, 0, 0);
  }
  const int r0 = by * 128 + wr + (lane >> 4) * 4;
  const int c0 = bx * 128 + wc + la;
#pragma unroll
  for (int i = 0; i < 4; ++i)
#pragma unroll
    for (int j = 0; j < 4; ++j) {
      int c = c0 + j * 16;
      float bv = bias[c];
#pragma unroll
      for (int q = 0; q < 4; ++q) {
        int r = r0 + i * 16 + q;
        float v = acc[i][j][q] + bv;
        if (epi == 1) v = (v > 0.0f) ? v : expm1f(v);
        Cbf[(size_t)r * N + c] = f2bf(v);
      }
    }
}

// ---------------------------------------------------------------------------
// Fused gate + pooling (per mailbox)
// ---------------------------------------------------------------------------
__global__ __launch_bounds__(256) void k_gate_pool(
    const ushort* __restrict__ o, const float* __restrict__ gw,
    ushort* __restrict__ ae, float* __restrict__ gsum) {
  __shared__ float os[8][1024];
  __shared__ float lg[8][4];
  __shared__ float gs[8][4];
  const int b = blockIdx.x, t = threadIdx.x;
  for (int u = t; u < 8192; u += 256) {
    int l = u >> 10, d = u & 1023;
    os[l][d] = bf2f(o[(size_t)(b * 8 + l) * 1024 + d]);
  }
  __syncthreads();
  {
    int p = t >> 3, sub = t & 7;
    int l = p >> 2, e = p & 3;
    float s = 0;
    for (int d = sub; d < 1024; d += 8) s += os[l][d] * gw[d * 4 + e];
    s += __shfl_down(s, 4, 8);
    s += __shfl_down(s, 2, 8);
    s += __shfl_down(s, 1, 8);
    if (sub == 0) lg[l][e] = s;
  }
  __syncthreads();
  if (t < 8) {
    float m = fmaxf(fmaxf(lg[t][0], lg[t][1]), fmaxf(lg[t][2], lg[t][3]));
    float e0 = expf(lg[t][0] - m), e1 = expf(lg[t][1] - m);
    float e2 = expf(lg[t][2] - m), e3 = expf(lg[t][3] - m);
    float inv = 1.0f / (e0 + e1 + e2 + e3);
    gs[t][0] = e0 * inv; gs[t][1] = e1 * inv;
    gs[t][2] = e2 * inv; gs[t][3] = e3 * inv;
  }
  __syncthreads();
  if (t < 4) {
    float g = 0;
#pragma unroll
    for (int l = 0; l < 8; ++l) g += gs[l][t];
    gsum[b * 4 + t] = g;
  }
#pragma unroll
  for (int rep = 0; rep < 4; ++rep) {
    int d = t + rep * 256;
    float a0 = 0, a1 = 0, a2 = 0, a3 = 0;
#pragma unroll
    for (int l = 0; l < 8; ++l) {
      float ov = os[l][d];
      a0 += gs[l][0] * ov; a1 += gs[l][1] * ov;
      a2 += gs[l][2] * ov; a3 += gs[l][3] * ov;
    }
    ae[(size_t)0 * 524288 + b * 1024 + d] = f2bf(a0);
    ae[(size_t)1 * 524288 + b * 1024 + d] = f2bf(a1);
    ae[(size_t)2 * 524288 + b * 1024 + d] = f2bf(a2);
    ae[(size_t)3 * 524288 + b * 1024 + d] = f2bf(a3);
  }
}

// ---------------------------------------------------------------------------
// Pooled MoE GEMM (experts folded into K-accumulation)
// ---------------------------------------------------------------------------
__global__ __launch_bounds__(256) void gemm_moe2(
    const ushort* __restrict__ AE, const ushort* __restrict__ Bt4,
    const float* __restrict__ expb, const float* __restrict__ gsum,
    float* __restrict__ out) {
  __shared__ ushort As[64 * 40];
  __shared__ ushort Bs[64 * 40];
  const int bx = blockIdx.x, by = blockIdx.y;
  const int t = threadIdx.x;
  const int wv = t >> 6, lane = t & 63;
  const int wr = (wv >> 1) * 32, wc = (wv & 1) * 32;
  const int srow = t >> 2, sq = t & 3;
  const int la = lane & 15, lk = (lane >> 4) * 8;
  const int sdst = srow * 40 + sq * 8;
  f32x4 acc[2][2];
  const f32x4 z4 = {0.f, 0.f, 0.f, 0.f};
  acc[0][0] = z4; acc[0][1] = z4; acc[1][0] = z4; acc[1][1] = z4;
  for (int e = 0; e < 4; ++e) {
    const ushort* Ag = AE + (size_t)e * 524288 + (size_t)(by * 64 + srow) * 1024 + sq * 8;
    const ushort* Bg = Bt4 + (size_t)e * 1048576 + (size_t)(bx * 64 + srow) * 1024 + sq * 8;
    uint4 ra = *reinterpret_cast<const uint4*>(Ag);
    uint4 rb = *reinterpret_cast<const uint4*>(Bg);
    for (int kt = 0; kt < 1024; kt += 32) {
      __syncthreads();
      *reinterpret_cast<uint4*>(&As[sdst]) = ra;
      *reinterpret_cast<uint4*>(&Bs[sdst]) = rb;
      __syncthreads();
      if (kt + 32 < 1024) {
        ra = *reinterpret_cast<const uint4*>(Ag + kt + 32);
        rb = *reinterpret_cast<const uint4*>(Bg + kt + 32);
      }
      short8v af[2], bfr[2];
#pragma unroll
      for (int i = 0; i < 2; ++i)
        af[i] = *reinterpret_cast<const short8v*>(&As[(wr + i * 16 + la) * 40 + lk]);
#pragma unroll
      for (int j = 0; j < 2; ++j)
        bfr[j] = *reinterpret_cast<const short8v*>(&Bs[(wc + j * 16 + la) * 40 + lk]);
#pragma unroll
      for (int i = 0; i < 2; ++i)
#pragma unroll
        for (int j = 0; j < 2; ++j)
          acc[i][j] = __builtin_amdgcn_mfma_f32_16x16x32_bf16(af[i], bfr[j], acc[i][j], 0, 0, 0);
    }
  }
  const int r0 = by * 64 + wr + (lane >> 4) * 4;
  const int c0 = bx * 64 + wc + la;
#pragma unroll
  for (int i = 0; i < 2; ++i)
#pragma unroll
    for (int q = 0; q < 4; ++q) {
      int r = r0 + i * 16 + q;
      float4 gv = *reinterpret_cast<const float4*>(gsum + r * 4);
#pragma unroll
      for (int j = 0; j < 2; ++j) {
        int c = c0 + j * 16;
        float bias = gv.x * expb[c] + gv.y * expb[1024 + c] +
                     gv.z * expb[2048 + c] + gv.w * expb[3072 + c];
        float s = (acc[i][j][q] + bias) * 0.125f;
        out[(size_t)r * 1024 + c] = 1.0f / (1.0f + expf(-s));
      }
    }
}

// ---------------------------------------------------------------------------
// Symmetric Gram contrastive kernel (2080 triangular tiles) — proven r8/r10
// ---------------------------------------------------------------------------
__global__ __launch_bounds__(256) void gram_sym(
    const ushort* __restrict__ W, float* __restrict__ rsum,
    float* __restrict__ d11, float* __restrict__ d12, float* __restrict__ d22) {
  __shared__ ushort As[128 * 40];
  __shared__ ushort Bs[128 * 40];
  int tt = blockIdx.x, bi = 0, cnt = 64;
  while (tt >= cnt) { tt -= cnt; ++bi; --cnt; }
  int bj = bi + tt;
  const bool diag = (bi == bj);
  const int t = threadIdx.x;
  const int wv = t >> 6, lane = t & 63;
  const int wr = (wv >> 1) * 64, wc = (wv & 1) * 64;
  const int srow = t >> 1, shalf = t & 1;
  const ushort* Ag = W + (size_t)(bi * 128 + srow) * 128 + shalf * 16;
  const ushort* Bg = W + (size_t)(bj * 128 + srow) * 128 + shalf * 16;
  uint4 ra0 = *reinterpret_cast<const uint4*>(Ag);
  uint4 ra1 = *reinterpret_cast<const uint4*>(Ag + 8);
  uint4 rb0 = *reinterpret_cast<const uint4*>(Bg);
  uint4 rb1 = *reinterpret_cast<const uint4*>(Bg + 8);
  f32x4 acc[4][4];
  const f32x4 z4 = {0.f, 0.f, 0.f, 0.f};
#pragma unroll
  for (int i = 0; i < 4; ++i)
#pragma unroll
    for (int j = 0; j < 4; ++j) acc[i][j] = z4;
  const int la = lane & 15, lk = (lane >> 4) * 8;
  const int sdst = srow * 40 + shalf * 16;
  for (int kt = 0; kt < 128; kt += 32) {
    __syncthreads();
    *reinterpret_cast<uint4*>(&As[sdst])     = ra0;
    *reinterpret_cast<uint4*>(&As[sdst + 8]) = ra1;
    *reinterpret_cast<uint4*>(&Bs[sdst])     = rb0;
    *reinterpret_cast<uint4*>(&Bs[sdst + 8]) = rb1;
    __syncthreads();
    if (kt + 32 < 128) {
      ra0 = *reinterpret_cast<const uint4*>(Ag + kt + 32);
      ra1 = *reinterpret_cast<const uint4*>(Ag + kt + 40);
      rb0 = *reinterpret_cast<const uint4*>(Bg + kt + 32);
      rb1 = *reinterpret_cast<const uint4*>(Bg + kt + 40);
    }
    short8v af[4], bfr[4];
#pragma unroll
    for (int i = 0; i < 4; ++i)
      af[i] = *reinterpret_cast<const short8v*>(&As[(wr + i * 16 + la) * 40 + lk]);
#pragma unroll
    for (int j = 0; j < 4; ++j)
      bfr[j] = *reinterpret_cast<const short8v*>(&Bs[(wc + j * 16 + la) * 40 + lk]);
#pragma unroll
    for (int i = 0; i < 4; ++i)
#pragma unroll
      for (int j = 0; j < 4; ++j)
        acc[i][j] = __builtin_amdgcn_mfma_f32_16x16x32_bf16(af[i], bfr[j], acc[i][j], 0, 0, 0);
  }
  const int r0 = bi * 128 + wr + (lane >> 4) * 4;
  const int c0 = bj * 128 + wc + la;
  constexpr float K2 = 2.8853900817779268f;   // 2 / ln(2)
  float rs[4][4];
  float cs[4] = {0.f, 0.f, 0.f, 0.f};
#pragma unroll
  for (int i = 0; i < 4; ++i)
#pragma unroll
    for (int q = 0; q < 4; ++q) rs[i][q] = 0.f;
#pragma unroll
  for (int i = 0; i < 4; ++i)
#pragma unroll
    for (int j = 0; j < 4; ++j)
#pragma unroll
      for (int q = 0; q < 4; ++q) {
        int r = r0 + i * 16 + q;
        int c = c0 + j * 16;
        float e = exp2f(K2 * acc[i][j][q]);
        rs[i][q] += e;
        cs[j] += e;
        if (c == r)        { if (r < 4096) d11[r] = e; else d22[r - 4096] = e; }
        if (c == r + 4096) d12[r] = e;
      }
#pragma unroll
  for (int m = 1; m < 16; m <<= 1)
#pragma unroll
    for (int i = 0; i < 4; ++i)
#pragma unroll
      for (int q = 0; q < 4; ++q) rs[i][q] += __shfl_xor(rs[i][q], m);
  float* rowdst = rsum + ((bj >= 32) ? 8192 : 0);
  if (la == 0) {
#pragma unroll
    for (int i = 0; i < 4; ++i)
#pragma unroll
      for (int q = 0; q < 4; ++q) atomAdd(&rowdst[r0 + i * 16 + q], rs[i][q]);
  }
  if (!diag) {
#pragma unroll
    for (int j = 0; j < 4; ++j) {
      cs[j] += __shfl_xor(cs[j], 16);
      cs[j] += __shfl_xor(cs[j], 32);
    }
    float* coldst = rsum + ((bi >= 32) ? 8192 : 0);
    if ((lane >> 4) == 0) {
#pragma unroll
      for (int j = 0; j < 4; ++j) atomAdd(&coldst[c0 + j * 16], cs[j]);
    }
  }
}

__global__ __launch_bounds__(256) void cl_row(
    const float* __restrict__ rsum, const float* __restrict__ d11,
    const float* __restrict__ d12, const float* __restrict__ d22,
    float* __restrict__ cl_sum) {
  __shared__ float sh[256];
  int i = blockIdx.x * 256 + threadIdx.x;
  float denA = rsum[i] + rsum[8192 + i] - d11[i];
  float denB = rsum[8192 + 4096 + i] + rsum[4096 + i] - d22[i];
  float l = 0.5f * (logf(denA) + logf(denB)) - logf(d12[i]);
  float s = blockReduce256(l, sh, threadIdx.x);
  if (threadIdx.x == 0) atomAdd(cl_sum, s);
}

// weight transpose + bf16 convert: Bt[n*K+k] = bf16(W[k*N+n])
__global__ __launch_bounds__(256) void k_wt_bt(const float* __restrict__ W,
                                               ushort* __restrict__ Bt, int K, int N) {
  __shared__ float tile[32][33];
  int n0 = blockIdx.x * 32, k0 = blockIdx.y * 32;
  int tx = threadIdx.x & 31, ty = threadIdx.x >> 5;
#pragma unroll
  for (int i = 0; i < 4; ++i)
    tile[ty + 8 * i][tx] = W[(size_t)(k0 + ty + 8 * i) * N + n0 + tx];
  __syncthreads();
#pragma unroll
  for (int i = 0; i < 4; ++i)
    Bt[(size_t)(n0 + ty + 8 * i) * K + k0 + tx] = f2bf(tile[tx][ty + 8 * i]);
}

// batched transpose: W strided by z
__global__ __launch_bounds__(256) void k_wt_bt_s(const float* __restrict__ Wbase,
                                                 ushort* __restrict__ Btbase, int K, int N) {
  __shared__ float tile[32][33];
  const float* W = Wbase + (size_t)blockIdx.z * K * N;
  ushort* Bt = Btbase + (size_t)blockIdx.z * K * N;
  int n0 = blockIdx.x * 32, k0 = blockIdx.y * 32;
  int tx = threadIdx.x & 31, ty = threadIdx.x >> 5;
#pragma unroll
  for (int i = 0; i < 4; ++i)
    tile[ty + 8 * i][tx] = W[(size_t)(k0 + ty + 8 * i) * N + n0 + tx];
  __syncthreads();
#pragma unroll
  for (int i = 0; i < 4; ++i)
    Bt[(size_t)(n0 + ty + 8 * i) * K + k0 + tx] = f2bf(tile[tx][ty + 8 * i]);
}

// batched transpose for 4 separate weight pointers (QKV + O)
__global__ __launch_bounds__(256) void k_wt_bt4(const float* __restrict__ w0,
                                                const float* __restrict__ w1,
                                                const float* __restrict__ w2,
                                                const float* __restrict__ w3,
                                                ushort* __restrict__ Btbase, int K, int N) {
  __shared__ float tile[32][33];
  const float* W = (blockIdx.z == 0) ? w0 : (blockIdx.z == 1) ? w1
                 : (blockIdx.z == 2) ? w2 : w3;
  ushort* Bt = Btbase + (size_t)blockIdx.z * K * N;
  int n0 = blockIdx.x * 32, k0 = blockIdx.y * 32;
  int tx = threadIdx.x & 31, ty = threadIdx.x >> 5;
#pragma unroll
  for (int i = 0; i < 4; ++i)
    tile[ty + 8 * i][tx] = W[(size_t)(k0 + ty + 8 * i) * N + n0 + tx];
  __syncthreads();
#pragma unroll
  for (int i = 0; i < 4; ++i)
    Bt[(size_t)(n0 + ty + 8 * i) * K + k0 + tx] = f2bf(tile[tx][ty + 8 * i]);
}

// ---------------------------------------------------------------------------
// Fused S post-process: SB bf16 write + MSG build + emb_sum partial.
// ---------------------------------------------------------------------------
__global__ __launch_bounds__(256) void k_post_s(
    const float* __restrict__ s1, const float* __restrict__ s2,
    const float* __restrict__ relation, const int* __restrict__ etype,
    ushort* __restrict__ sb, ushort* __restrict__ msg, float* __restrict__ emb_out) {
  __shared__ float sh[256];
  float part = 0.f;
  for (int idx = blockIdx.x * 256 + threadIdx.x; idx < 1048576; idx += 128 * 256) {
    float vs = (idx < 524288) ? s1[idx] : s2[idx - 524288];
    sb[idx] = f2bf(vs);
    int i = idx >> 8, j = idx & 255;
    int et = etype[i];
    float sign = (et >= cNR) ? -1.0f : 1.0f;
    float r = relation[(size_t)(et % cNR) * 256 + j];
    float s = (j < 128) ? s1[(size_t)i * 128 + j] : s2[(size_t)i * 128 + j - 128];
    msg[idx] = f2bf(fmaxf(s + r * sign, 0.0f));
    part += s * s + r * r;
  }
  float tot = blockReduce256(part, sh, threadIdx.x);
  if (threadIdx.x == 0) atomAdd(emb_out, tot);
}

// in-place bf16 row normalize (wave reduction, 1 sync)
__global__ __launch_bounds__(128) void rownorm_bf2(ushort* __restrict__ w) {
  __shared__ float sh[2];
  int i = blockIdx.x, tid = threadIdx.x;
  float v = bf2f(w[(size_t)i * cD + tid]);
  float ss = v * v;
#pragma unroll
  for (int off = 32; off > 0; off >>= 1) ss += __shfl_xor(ss, off);
  if ((tid & 63) == 0) sh[tid >> 6] = ss;
  __syncthreads();
  float n = fmaxf(sqrtf(sh[0] + sh[1]), 1e-12f);
  w[(size_t)i * cD + tid] = f2bf(v / n);
}

// fused-QKV attention: qkv [4096][3072], o [4096][1024] bf16
__global__ __launch_bounds__(64) void mha_attn(
    const ushort* __restrict__ qkv, ushort* __restrict__ o) {
  __shared__ float qs[8][132], ks[8][132], vs[8][132];
  __shared__ float att[8][8];
  int bh = blockIdx.x;
  int b = bh >> 3, h = bh & 7;
  int tid = threadIdx.x;
  for (int u = tid; u < 256; u += 64) {
    int l = u >> 5;
    int d4 = (u & 31) * 4;
    size_t base = (size_t)(b * 8 + l) * 3072 + h * 128 + d4;
    ushort4 qv = *reinterpret_cast<const ushort4*>(qkv + base);
    ushort4 kv = *reinterpret_cast<const ushort4*>(qkv + base + 1024);
    ushort4 vv = *reinterpret_cast<const ushort4*>(qkv + base + 2048);
    qs[l][d4] = bf2f(qv.x); qs[l][d4 + 1] = bf2f(qv.y);
    qs[l][d4 + 2] = bf2f(qv.z); qs[l][d4 + 3] = bf2f(qv.w);
    ks[l][d4] = bf2f(kv.x); ks[l][d4 + 1] = bf2f(kv.y);
    ks[l][d4 + 2] = bf2f(kv.z); ks[l][d4 + 3] = bf2f(kv.w);
    vs[l][d4] = bf2f(vv.x); vs[l][d4 + 1] = bf2f(vv.y);
    vs[l][d4 + 2] = bf2f(vv.z); vs[l][d4 + 3] = bf2f(vv.w);
  }
  __syncthreads();
  int l = tid >> 3, m = tid & 7;
  const float4* qp = reinterpret_cast<const float4*>(&qs[l][0]);
  const float4* kp = reinterpret_cast<const float4*>(&ks[m][0]);
  float s = 0;
#pragma unroll
  for (int d4 = 0; d4 < 32; ++d4) {
    float4 a = qp[d4], bb = kp[d4];
    s += a.x * bb.x + a.y * bb.y + a.z * bb.z + a.w * bb.w;
  }
  s *= 0.08838834764831845f;
  float mx = s;
  for (int off = 1; off < 8; off <<= 1) mx = fmaxf(mx, __shfl_xor(mx, off, 8));
  float p = expf(s - mx);
  float sum = p;
  for (int off = 1; off < 8; off <<= 1) sum += __shfl_xor(sum, off, 8);
  att[l][m] = p / sum;
  __syncthreads();
  for (int u = tid; u < 1024; u += 64) {
    int ll = u >> 7, d = u & 127;
    float acc = 0;
#pragma unroll
    for (int mm = 0; mm < 8; ++mm) acc += att[ll][mm] * vs[mm][d];
    o[(size_t)(b * 8 + ll) * 1024 + h * 128 + d] = f2bf(acc);
  }
}

__global__ void finalize_k(const float* __restrict__ scal, float* __restrict__ out_aux) {
  float cl = scal[0] * (1.0f / cNSRC);
  float emb = cDECAY * 0.5f * scal[1] * (1.0f / cNSRC);
  out_aux[0] = cCLW * cl + emb;
}

// ---------------------------------------------------------------------------
// Launch
// ---------------------------------------------------------------------------
extern "C" void kernel_launch(void* const* d_in, const int* in_sizes, int n_in,
                              void* d_out, int out_size, void* d_ws, size_t ws_size,
                              hipStream_t stream) {
  (void)in_sizes; (void)n_in; (void)out_size; (void)ws_size;
  const float* entity   = (const float*)d_in[0];
  const float* type_e   = (const float*)d_in[1];
  const float* cluster  = (const float*)d_in[2];
  const float* relation = (const float*)d_in[3];
  const float* ln_g  = (const float*)d_in[4];
  const float* ln_b  = (const float*)d_in[5];
  const float* cl_w1 = (const float*)d_in[6];
  const float* cl_b1 = (const float*)d_in[7];
  const float* cl_w2 = (const float*)d_in[8];
  const float* cl_b2 = (const float*)d_in[9];
  const float* fc_w  = (const float*)d_in[10];
  const float* fc_b  = (const float*)d_in[11];
  const float* wq = (const float*)d_in[12];
  const float* bq = (const float*)d_in[13];
  const float* wk = (const float*)d_in[14];
  const float* bk = (const float*)d_in[15];
  const float* wv = (const float*)d_in[16];
  const float* bv = (const float*)d_in[17];
  const float* wo = (const float*)d_in[18];
  const float* bo = (const float*)d_in[19];
  const float* gate_w = (const float*)d_in[20];
  const float* exp_w  = (const float*)d_in[21];
  const float* exp_b  = (const float*)d_in[22];
  const float* e2t_val = (const float*)d_in[23];
  const float* t2c_val = (const float*)d_in[24];
  const float* e2c_val = (const float*)d_in[25];
  const int* e2t_row = (const int*)d_in[26];
  const int* e2t_col = (const int*)d_in[27];
  const int* t2c_row = (const int*)d_in[28];
  const int* t2c_col = (const int*)d_in[29];
  const int* e2c_row = (const int*)d_in[30];
  const int* e2c_col = (const int*)d_in[31];
  const int* src_ids = (const int*)d_in[32];
  const int* etype   = (const int*)d_in[33];

  float* ws = (float*)d_ws;
  float* S1 = ws + F_S1;
  float* S2 = ws + F_S2;
  ushort* Wbf = (ushort*)(ws + F_PT);
  ushort* P1bf = (ushort*)(ws + F_Z1);
  ushort* SBbf = (ushort*)(ws + F_Z2);
  ushort* MSGbf = (ushort*)(ws + F_MSG);
  float* GSUM = ws + F_GATE;
  float* SCAL = ws + F_SCAL;
  float* RS   = ws + F_RS;
  float* BQKV = ws + F_GATE + 8192;
  float* D11  = ws + F_D11;
  float* D12  = ws + F_D12;
  float* D22  = ws + F_D22;
  ushort* X1F = (ushort*)(ws + G_X1F);
  ushort* X2C = (ushort*)(ws + G_X2C);
  int*   MARK = (int*)(ws + G_X2C);     // aliased: dead before X2C written
  int*   SLOT = (int*)(ws + G_SLOT);
  int*   REP  = (int*)(ws + G_REP);
  int*   RP   = (int*)(ws + G_RP);
  int*   FILL = (int*)(ws + G_FILL);
  int*   COLS = (int*)(ws + G_COLS);
  float* VALS = ws + G_VALS;
  ushort* X1T = (ushort*)(ws + G_X1T);
  ushort* X2T = (ushort*)(ws + G_X2T);
  int*   BSUM = (int*)(ws + G_BSUM);
  ushort* EBF = (ushort*)(ws + G_EBF);
  ushort* TBF = (ushort*)(ws + G_TBF);
  ushort* CBF = (ushort*)(ws + G_CBF);
  ushort* PB   = (ushort*)(ws + A_U0);
  ushort* AE   = (ushort*)(ws + A_U0);
  ushort* QKV  = (ushort*)(ws + A_U1);
  ushort* OB   = (ushort*)(ws + A_U1);
  ushort* WBT  = (ushort*)(ws + A_WBT);

  hipMemsetAsync(SCAL, 0, 2 * sizeof(float), stream);
  hipMemsetAsync(RS, 0, (16384 + 3 * 4096) * sizeof(float), stream);

  // bf16 embedding tables (once)
  k_to_bf<<<2048, 256, 0, stream>>>(entity, EBF, cNE * cD / 4);
  k_to_bf<<<128, 256, 0, stream>>>(type_e, TBF, cNT * cD / 4);
  k_to_bf<<<16, 256, 0, stream>>>(cluster, CBF, cNC * cD / 4);

  // masked GCN
  auto run_gcn_masked = [&](const int* row, const int* col, const float* val, int nnz, int nn,
                            const float* ea_f, const float* eb_f,
                            const ushort* ea_b, const ushort* eb_b, int na, int mode,
                            float* dst) {
    int nb = (nn + 255) / 256;
    int gEdge = (nnz + 255) / 256;
    k_init3<<<nb, 256, 0, stream>>>(SLOT, MARK, FILL, nn);
    k_slot_mark<<<16, 256, 0, stream>>>(src_ids, SLOT, MARK, mode);
    k_mark_edges<<<gEdge, 256, 0, stream>>>(row, col, nnz, SLOT, MARK);
    k_hist<<<gEdge, 256, 0, stream>>>(row, nnz, MARK, FILL);
    k_scan_block<<<nb, 256, 0, stream>>>(FILL, nn, RP, BSUM);
    k_bsum_scan<<<1, 512, 0, stream>>>(BSUM, nb, RP, nn);
    k_scan_add<<<nb, 256, 0, stream>>>(RP, BSUM, nn, FILL);
    k_fill<<<gEdge, 256, 0, stream>>>(row, col, val, nnz, MARK, FILL, COLS, VALS);
    k_rep<<<16, 256, 0, stream>>>(src_ids, SLOT, mode, REP);
    k_gather<<<(nn + 3) / 4, 256, 0, stream>>>(RP, COLS, VALS, ea_b, eb_b, na, nn, MARK, X1F);
    k_gather_slot<<<cNSRC / 4, 256, 0, stream>>>(RP, COLS, VALS, X1F, REP, X2C);
    gather_ln<<<cNSRC, 128, 0, stream>>>(src_ids, mode, ea_f, eb_f, na, X1F, X2C, SLOT,
                                         ln_g, ln_b, dst);
  };

  run_gcn_masked(e2t_row, e2t_col, e2t_val, cNNZ_E2T, cNN_E2T,
                 entity, type_e, EBF, TBF, cNE, 0, S1);
  run_gcn_masked(e2c_row, e2c_col, e2c_val, cNNZ_E2C, cNN_E2C,
                 entity, cluster, EBF, CBF, cNE, 3, S2);

  // ---- t2c: tiny, both layers full ----
  {
    int nn = cNN_T2C, nb = (nn + 255) / 256, gEdge = (cNNZ_T2C + 255) / 256;
    hipMemsetAsync(FILL, 0, (size_t)nn * sizeof(int), stream);
    k_hist<<<gEdge, 256, 0, stream>>>(t2c_row, cNNZ_T2C, nullptr, FILL);
    k_scan_block<<<nb, 256, 0, stream>>>(FILL, nn, RP, BSUM);
    k_bsum_scan<<<1, 512, 0, stream>>>(BSUM, nb, RP, nn);
    k_scan_add<<<nb, 256, 0, stream>>>(RP, BSUM, nn, FILL);
    k_fill<<<gEdge, 256, 0, stream>>>(t2c_row, t2c_col, t2c_val, cNNZ_T2C, nullptr,
                                      FILL, COLS, VALS);
    k_gather<<<(nn + 3) / 4, 256, 0, stream>>>(RP, COLS, VALS, TBF, CBF, cNT,
                                               nn, nullptr, X1T);
    k_gather_bf<<<(nn + 3) / 4, 256, 0, stream>>>(RP, COLS, VALS, X1T, nn, X2T);
    gather_ln<<<cNSRC, 128, 0, stream>>>(src_ids, 1, type_e, cluster, cNT, X1T, X2T, nullptr,
                                         ln_g, ln_b, S1);
    gather_ln<<<cNSRC, 128, 0, stream>>>(src_ids, 2, type_e, cluster, cNT, X1T, X2T, nullptr,
                                         ln_g, ln_b, S2);
  }

  // ================= fused S post-process (SB + MSG + emb_sum) =================
  k_post_s<<<128, 256, 0, stream>>>(S1, S2, relation, etype, SBbf, MSGbf, SCAL + 1);

  // ================= contrastive loss =================
  ushort* W1T = WBT;
  ushort* W2T = WBT + 16384;
  k_wt_bt<<<dim3(4, 4), 256, 0, stream>>>(cl_w1, W1T, cD, cD);
  k_wt_bt<<<dim3(4, 4), 256, 0, stream>>>(cl_w2, W2T, cD, cD);
  gemm_bf<<<dim3(1, 64), 256, 0, stream>>>(SBbf, W1T, cD, cD, cl_b1, P1bf, 1);
  gemm_bf<<<dim3(1, 64), 256, 0, stream>>>(P1bf, W2T, cD, cD, cl_b2, Wbf, 0);
  rownorm_bf2<<<2 * cNSRC, 128, 0, stream>>>(Wbf);
  gram_sym<<<2080, 256, 0, stream>>>(Wbf, RS, D11, D12, D22);
  cl_row<<<16, 256, 0, stream>>>(RS, D11, D12, D22, SCAL);

  // ================= predict =================
  k_wt_bt<<<dim3(cT / 32, 256 / 32), 256, 0, stream>>>(fc_w, WBT, 256, cT);
  gemm_bf<<<dim3(cT / 128, cNSRC / 128), 256, 0, stream>>>(MSGbf, WBT, cT, 256, fc_b, PB, 0);

  // ================= MHA: fused QKV (+O weight pre-transposed) =================
  k_wt_bt4<<<dim3(32, 32, 4), 256, 0, stream>>>(wq, wk, wv, wo, WBT, cT, cT);
  k_pack_bias<<<12, 256, 0, stream>>>(bq, bk, bv, BQKV);
  gemm_bf<<<dim3(3072 / 128, cNSRC / 128), 256, 0, stream>>>(PB, WBT, 3072, cT, BQKV, QKV, 0);
  mha_attn<<<cB * 8, 64, 0, stream>>>(QKV, PB);
  gemm_bf<<<dim3(cT / 128, cNSRC / 128), 256, 0, stream>>>(PB, WBT + 3 * 1048576, cT, cT,
                                                           bo, OB, 0);

  // ================= pooled MoE =================
  k_gate_pool<<<cB, 256, 0, stream>>>(OB, gate_w, AE, GSUM);
  k_wt_bt_s<<<dim3(32, 32, 4), 256, 0, stream>>>(exp_w, WBT, cT, cT);
  gemm_moe2<<<dim3(16, 8), 256, 0, stream>>>(AE, WBT, exp_b, GSUM, (float*)d_out);

  finalize_k<<<1, 1, 0, stream>>>(SCAL, (float*)d_out + (size_t)cB * cT);
}

// Round 15
// 490.832 us; speedup vs baseline: 1.1317x; 1.0767x over previous
//
#include <hip/hip_runtime.h>
#include <hip/hip_bf16.h>
#include <cmath>

// ---------------------------------------------------------------------------
// Problem constants (fixed shapes)
// ---------------------------------------------------------------------------
constexpr int cNE = 100000, cNT = 1024, cNC = 128, cD = 128, cNR = 500;
constexpr int cB = 512, cNSRC = 4096, cT = 1024, cE = 4;
constexpr int cNNZ_E2T = 1000000, cNNZ_T2C = 50000, cNNZ_E2C = 500000;
constexpr float cDECAY = 1e-4f, cCLW = 0.1f;
constexpr int cNN_E2T = cNE + cNT;     // 101024
constexpr int cNN_E2C = cNE + cNC;     // 100128
constexpr int cNN_T2C = cNT + cNC;     // 1152
// per-graph strides / offsets for batched CSR buffers
constexpr int SL_STR = 101376;         // slot/mark/fill stride (mult of 256)
constexpr int RP_STR = 101400;         // rowptr stride (>= nn+1)
constexpr int CO_E2T = 0, CO_E2C = 1000000, CO_T2C = 1500000;

// ---------------------------------------------------------------------------
// Workspace layout (FLOAT units)
// ---------------------------------------------------------------------------
constexpr size_t F_S1   = 0;                          // f32 4096x128
constexpr size_t F_S2   = F_S1 + 524288;
constexpr size_t F_PT   = F_S2 + 524288;              // bf16 W [8192][128]
constexpr size_t F_Z1   = F_PT + 524288;              // bf16 P1
constexpr size_t F_Z2   = F_Z1 + 524288;              // bf16 SB
constexpr size_t F_MSG  = F_Z2 + 524288;              // bf16 4096x256
constexpr size_t F_GATE = F_MSG + 524288;             // f32 GSUM [512][4]
constexpr size_t F_SCAL = F_GATE + 16384;
constexpr size_t F_RS   = F_SCAL + 64;                // f32 [2][8192]
constexpr size_t F_D11  = F_RS + 16384;
constexpr size_t F_D12  = F_D11 + 4096;
constexpr size_t F_D22  = F_D12 + 4096;
constexpr size_t F_U    = F_D22 + 4096;               // union base
// --- GCN phase (batched CSR buffers) ---
constexpr size_t G_X1F  = F_U;                        // ushort[101024*128]
constexpr size_t G_X2C  = G_X1F + 6465536;            // ushort[4096*128]
constexpr size_t G_SLOT = G_X2C + 262144;             // int[2*SL_STR]
constexpr size_t G_MARK = G_SLOT + 202752;            // int[2*SL_STR]
constexpr size_t G_REP  = G_MARK + 202752;            // int[2*4096]
constexpr size_t G_RP   = G_REP + 8192;               // int[3*RP_STR]
constexpr size_t G_FILL = G_RP + 304200;              // int[3*SL_STR]
constexpr size_t G_BSUM = G_FILL + 304128;            // int[3*512]
constexpr size_t G_COLS = G_BSUM + 1536;              // int[1550000]
constexpr size_t G_VALS = G_COLS + 1550000;           // f32[1550000]
constexpr size_t G_X1T  = G_VALS + 1550000;           // ushort[1152*128]
constexpr size_t G_X2T  = G_X1T + 73728;
constexpr size_t G_EBF  = G_X2T + 73728;              // ushort[100000*128]
constexpr size_t G_TBF  = G_EBF + 3200000;            // ushort[1024*128]
constexpr size_t G_CBF  = G_TBF + 65536;              // ushort[128*128]
// --- activation phase ---
constexpr size_t A_U0  = F_U;
constexpr size_t A_U1  = F_U + 2097152;
constexpr size_t A_WBT = F_U + 4 * 2097152;

typedef __attribute__((ext_vector_type(8))) short short8v;
typedef __attribute__((ext_vector_type(4))) float f32x4;

// ---------------------------------------------------------------------------
// Helpers
// ---------------------------------------------------------------------------
__device__ __forceinline__ void atomAdd(float* p, float v) {
  __hip_atomic_fetch_add(p, v, __ATOMIC_RELAXED, __HIP_MEMORY_SCOPE_AGENT);
}
__device__ __forceinline__ ushort f2bf(float f) {
  __hip_bfloat16 h = __float2bfloat16(f);
  return *reinterpret_cast<ushort*>(&h);
}
__device__ __forceinline__ float bf2f(ushort u) {
  __hip_bfloat16 h; *reinterpret_cast<ushort*>(&h) = u;
  return __bfloat162float(h);
}

__device__ __forceinline__ int mapNode(int mode, int id) {
  switch (mode) {
    case 0:  return (id < cNE + cNT) ? id : -1;
    case 1:  return (id >= cNE + cNT) ? (id - cNE) : -1;
    case 2:  return (id >= cNE && id < cNE + cNT) ? (id - cNE) : -1;
    default: return (id < cNE) ? id
                   : ((id >= cNE + cNT) ? (id - cNT) : -1);
  }
}

__device__ __forceinline__ float blockReduce256(float v, float* sh, int tid) {
  sh[tid] = v; __syncthreads();
  for (int s = 128; s > 0; s >>= 1) {
    if (tid < s) sh[tid] += sh[tid + s];
    __syncthreads();
  }
  float r = sh[0]; __syncthreads();
  return r;
}

// ---------------------------------------------------------------------------
// fused f32 -> bf16 table conversion (all three tables in one launch)
// ---------------------------------------------------------------------------
__global__ __launch_bounds__(256) void k_to_bf3(
    const float* __restrict__ se, const float* __restrict__ st, const float* __restrict__ sc,
    ushort* __restrict__ de, ushort* __restrict__ dt, ushort* __restrict__ dc) {
  constexpr int NQE = cNE * cD / 4;          // 3,200,000
  constexpr int NQT = cNT * cD / 4;          // 32,768
  constexpr int NQC = cNC * cD / 4;          // 4,096
  for (int q = blockIdx.x * 256 + threadIdx.x; q < NQE + NQT + NQC; q += gridDim.x * 256) {
    const float* src; ushort* dst; int qq;
    if (q < NQE)            { src = se; dst = de; qq = q; }
    else if (q < NQE + NQT) { src = st; dst = dt; qq = q - NQE; }
    else                    { src = sc; dst = dc; qq = q - NQE - NQT; }
    float4 v = *reinterpret_cast<const float4*>(src + (size_t)qq * 4);
    ushort4 o;
    o.x = f2bf(v.x); o.y = f2bf(v.y); o.z = f2bf(v.z); o.w = f2bf(v.w);
    *reinterpret_cast<ushort4*>(dst + (size_t)qq * 4) = o;
  }
}

// pack bq|bk|bv into one 3072-float buffer
__global__ __launch_bounds__(256) void k_pack_bias(const float* __restrict__ b0,
                                                   const float* __restrict__ b1,
                                                   const float* __restrict__ b2,
                                                   float* __restrict__ dst) {
  int i = blockIdx.x * 256 + threadIdx.x;   // 3072 total
  float v = (i < 1024) ? b0[i] : (i < 2048) ? b1[i - 1024] : b2[i - 2048];
  dst[i] = v;
}

// ---------------------------------------------------------------------------
// z-batched CSR build (z=0: e2t, z=1: e2c, z=2: t2c)
// ---------------------------------------------------------------------------
__global__ __launch_bounds__(256) void k_csr_init3(int* __restrict__ slotb,
                                                   int* __restrict__ markb,
                                                   int* __restrict__ fillb) {
  const int nn3[3] = {cNN_E2T, cNN_E2C, cNN_T2C};
  int z = blockIdx.z;
  int i = blockIdx.x * 256 + threadIdx.x;
  if (i >= nn3[z]) return;
  fillb[z * SL_STR + i] = 0;
  if (z < 2) {
    slotb[z * SL_STR + i] = 0x7f7f7f7f;
    markb[z * SL_STR + i] = 0;
  }
}

__global__ __launch_bounds__(256) void k_slot_mark2(const int* __restrict__ ids,
                                                    int* __restrict__ slotb,
                                                    int* __restrict__ markb) {
  int z = blockIdx.z;
  int mode = z ? 3 : 0;
  int i = blockIdx.x * 256 + threadIdx.x;
  if (i >= cNSRC) return;
  int node = mapNode(mode, ids[i]);
  if (node >= 0) { atomicMin(&slotb[z * SL_STR + node], i); markb[z * SL_STR + node] = 1; }
}

__global__ __launch_bounds__(256) void k_mark_edges2(
    const int* __restrict__ r0, const int* __restrict__ c0,
    const int* __restrict__ r1, const int* __restrict__ c1,
    const int* __restrict__ slotb, int* __restrict__ markb) {
  int z = blockIdx.z;
  int nnzv = z ? cNNZ_E2C : cNNZ_E2T;
  int e = blockIdx.x * 256 + threadIdx.x;
  if (e >= nnzv) return;
  const int* row = z ? r1 : r0;
  const int* col = z ? c1 : c0;
  int r = row[e];
  if (slotb[z * SL_STR + r] < cNSRC) markb[z * SL_STR + col[e]] = 1;
}

__global__ __launch_bounds__(256) void k_hist3(
    const int* __restrict__ r0, const int* __restrict__ r1, const int* __restrict__ r2,
    const int* __restrict__ markb, int* __restrict__ fillb) {
  const int nnz3[3] = {cNNZ_E2T, cNNZ_E2C, cNNZ_T2C};
  int z = blockIdx.z;
  int e = blockIdx.x * 256 + threadIdx.x;
  if (e >= nnz3[z]) return;
  const int* row = (z == 0) ? r0 : (z == 1) ? r1 : r2;
  int r = row[e];
  if (z < 2 && !markb[z * SL_STR + r]) return;
  atomicAdd(&fillb[z * SL_STR + r], 1);
}

__global__ __launch_bounds__(256) void k_scan_block3(const int* __restrict__ fillb,
                                                     int* __restrict__ rpb,
                                                     int* __restrict__ bsumb) {
  __shared__ int sh[256];
  const int nn3[3] = {cNN_E2T, cNN_E2C, cNN_T2C};
  int z = blockIdx.z;
  int n = nn3[z];
  int tid = threadIdx.x;
  int i = blockIdx.x * 256 + tid;
  int v = (i < n) ? fillb[z * SL_STR + i] : 0;
  sh[tid] = v; __syncthreads();
  for (int off = 1; off < 256; off <<= 1) {
    int t = (tid >= off) ? sh[tid - off] : 0;
    __syncthreads();
    sh[tid] += t;
    __syncthreads();
  }
  if (i < n) rpb[z * RP_STR + i] = sh[tid] - v;
  if (tid == 255) bsumb[z * 512 + blockIdx.x] = sh[255];
}

__global__ __launch_bounds__(512) void k_bsum_scan3(int* __restrict__ bsumb,
                                                    int* __restrict__ rpb) {
  __shared__ int sh[512];
  const int nn3[3] = {cNN_E2T, cNN_E2C, cNN_T2C};
  int z = blockIdx.x;
  int n = nn3[z];
  int tid = threadIdx.x;
  int v = (tid < 396) ? bsumb[z * 512 + tid] : 0;
  sh[tid] = v; __syncthreads();
  for (int off = 1; off < 512; off <<= 1) {
    int t = (tid >= off) ? sh[tid - off] : 0;
    __syncthreads();
    sh[tid] += t;
    __syncthreads();
  }
  if (tid < 396) bsumb[z * 512 + tid] = sh[tid] - v;
  if (tid == 511) rpb[z * RP_STR + n] = sh[511];
}

__global__ __launch_bounds__(256) void k_scan_add3(int* __restrict__ rpb,
                                                   const int* __restrict__ bsumb,
                                                   int* __restrict__ fillb) {
  const int nn3[3] = {cNN_E2T, cNN_E2C, cNN_T2C};
  int z = blockIdx.z;
  int i = blockIdx.x * 256 + threadIdx.x;
  if (i < nn3[z]) {
    int r = rpb[z * RP_STR + i] + bsumb[z * 512 + blockIdx.x];
    rpb[z * RP_STR + i] = r;
    fillb[z * SL_STR + i] = r;
  }
}

__global__ __launch_bounds__(256) void k_fill3(
    const int* __restrict__ r0, const int* __restrict__ c0, const float* __restrict__ v0,
    const int* __restrict__ r1, const int* __restrict__ c1, const float* __restrict__ v1,
    const int* __restrict__ r2, const int* __restrict__ c2, const float* __restrict__ v2,
    const int* __restrict__ markb, int* __restrict__ fillb,
    int* __restrict__ colsb, float* __restrict__ valsb) {
  const int nnz3[3] = {cNNZ_E2T, cNNZ_E2C, cNNZ_T2C};
  const int coff[3] = {CO_E2T, CO_E2C, CO_T2C};
  int z = blockIdx.z;
  int e = blockIdx.x * 256 + threadIdx.x;
  if (e >= nnz3[z]) return;
  const int* row = (z == 0) ? r0 : (z == 1) ? r1 : r2;
  const int* col = (z == 0) ? c0 : (z == 1) ? c1 : c2;
  const float* val = (z == 0) ? v0 : (z == 1) ? v1 : v2;
  int r = row[e];
  if (z < 2 && !markb[z * SL_STR + r]) return;
  int pos = atomicAdd(&fillb[z * SL_STR + r], 1);
  colsb[coff[z] + pos] = col[e];
  valsb[coff[z] + pos] = val[e];
}

__global__ __launch_bounds__(256) void k_rep2(const int* __restrict__ ids,
                                              const int* __restrict__ slotb,
                                              int* __restrict__ repb) {
  int z = blockIdx.z;
  int mode = z ? 3 : 0;
  int i = blockIdx.x * 256 + threadIdx.x;
  if (i >= cNSRC) return;
  int node = mapNode(mode, ids[i]);
  repb[z * 4096 + i] = (node >= 0 && slotb[z * SL_STR + node] == i) ? node : -1;
}

// ---------------------------------------------------------------------------
// wave-per-row gather, bf16 tables in -> bf16 out (4-wide unrolled)
// ---------------------------------------------------------------------------
__global__ __launch_bounds__(256) void k_gather(
    const int* __restrict__ rowptr, const int* __restrict__ cols, const float* __restrict__ vals,
    const ushort* __restrict__ ea, const ushort* __restrict__ eb, int na,
    int nrows, const int* __restrict__ mark, ushort* __restrict__ out) {
  int r = blockIdx.x * 4 + (threadIdx.x >> 6);
  if (r >= nrows) return;
  if (mark && !mark[r]) return;
  int lane = threadIdx.x & 63;
  int p0 = rowptr[r], p1 = rowptr[r + 1];
  float ax = 0.f, ay = 0.f;
  int p = p0;
  for (; p + 4 <= p1; p += 4) {
    int c0 = cols[p], c1 = cols[p + 1], c2 = cols[p + 2], c3 = cols[p + 3];
    float v0 = vals[p], v1 = vals[p + 1], v2 = vals[p + 2], v3 = vals[p + 3];
    const ushort* s0 = (c0 < na) ? (ea + (size_t)c0 * cD) : (eb + (size_t)(c0 - na) * cD);
    const ushort* s1 = (c1 < na) ? (ea + (size_t)c1 * cD) : (eb + (size_t)(c1 - na) * cD);
    const ushort* s2 = (c2 < na) ? (ea + (size_t)c2 * cD) : (eb + (size_t)(c2 - na) * cD);
    const ushort* s3 = (c3 < na) ? (ea + (size_t)c3 * cD) : (eb + (size_t)(c3 - na) * cD);
    ushort2 x0 = *reinterpret_cast<const ushort2*>(s0 + lane * 2);
    ushort2 x1 = *reinterpret_cast<const ushort2*>(s1 + lane * 2);
    ushort2 x2 = *reinterpret_cast<const ushort2*>(s2 + lane * 2);
    ushort2 x3 = *reinterpret_cast<const ushort2*>(s3 + lane * 2);
    ax += v0 * bf2f(x0.x) + v1 * bf2f(x1.x) + v2 * bf2f(x2.x) + v3 * bf2f(x3.x);
    ay += v0 * bf2f(x0.y) + v1 * bf2f(x1.y) + v2 * bf2f(x2.y) + v3 * bf2f(x3.y);
  }
  for (; p < p1; ++p) {
    int c = cols[p];
    float v = vals[p];
    const ushort* s = (c < na) ? (ea + (size_t)c * cD) : (eb + (size_t)(c - na) * cD);
    ushort2 x = *reinterpret_cast<const ushort2*>(s + lane * 2);
    ax += v * bf2f(x.x); ay += v * bf2f(x.y);
  }
  ushort2 o; o.x = f2bf(ax); o.y = f2bf(ay);
  *reinterpret_cast<ushort2*>(out + (size_t)r * cD + lane * 2) = o;
}

// layer-2 gather at representative slots (4-wide unrolled)
__global__ __launch_bounds__(256) void k_gather_slot(
    const int* __restrict__ rowptr, const int* __restrict__ cols, const float* __restrict__ vals,
    const ushort* __restrict__ x1, const int* __restrict__ rep,
    ushort* __restrict__ outc) {
  int i = blockIdx.x * 4 + (threadIdx.x >> 6);
  if (i >= cNSRC) return;
  int r = rep[i];
  if (r < 0) return;
  int lane = threadIdx.x & 63;
  int p0 = rowptr[r], p1 = rowptr[r + 1];
  float ax = 0.f, ay = 0.f;
  int p = p0;
  for (; p + 4 <= p1; p += 4) {
    int c0 = cols[p], c1 = cols[p + 1], c2 = cols[p + 2], c3 = cols[p + 3];
    float v0 = vals[p], v1 = vals[p + 1], v2 = vals[p + 2], v3 = vals[p + 3];
    ushort2 x0 = *reinterpret_cast<const ushort2*>(x1 + (size_t)c0 * cD + lane * 2);
    ushort2 x1v = *reinterpret_cast<const ushort2*>(x1 + (size_t)c1 * cD + lane * 2);
    ushort2 x2 = *reinterpret_cast<const ushort2*>(x1 + (size_t)c2 * cD + lane * 2);
    ushort2 x3 = *reinterpret_cast<const ushort2*>(x1 + (size_t)c3 * cD + lane * 2);
    ax += v0 * bf2f(x0.x) + v1 * bf2f(x1v.x) + v2 * bf2f(x2.x) + v3 * bf2f(x3.x);
    ay += v0 * bf2f(x0.y) + v1 * bf2f(x1v.y) + v2 * bf2f(x2.y) + v3 * bf2f(x3.y);
  }
  for (; p < p1; ++p) {
    int c = cols[p];
    float v = vals[p];
    ushort2 x = *reinterpret_cast<const ushort2*>(x1 + (size_t)c * cD + lane * 2);
    ax += v * bf2f(x.x); ay += v * bf2f(x.y);
  }
  ushort2 o; o.x = f2bf(ax); o.y = f2bf(ay);
  *reinterpret_cast<ushort2*>(outc + (size_t)i * cD + lane * 2) = o;
}

// full-row gather, bf16 in -> bf16 out (t2c layer 2)
__global__ __launch_bounds__(256) void k_gather_bf(
    const int* __restrict__ rowptr, const int* __restrict__ cols, const float* __restrict__ vals,
    const ushort* __restrict__ x1, int nrows, ushort* __restrict__ out) {
  int r = blockIdx.x * 4 + (threadIdx.x >> 6);
  if (r >= nrows) return;
  int lane = threadIdx.x & 63;
  int p0 = rowptr[r], p1 = rowptr[r + 1];
  float ax = 0.f, ay = 0.f;
  for (int p = p0; p < p1; ++p) {
    int c = cols[p];
    float v = vals[p];
    ushort2 x = *reinterpret_cast<const ushort2*>(x1 + (size_t)c * cD + lane * 2);
    ax += v * bf2f(x.x); ay += v * bf2f(x.y);
  }
  ushort2 o; o.x = f2bf(ax); o.y = f2bf(ay);
  *reinterpret_cast<ushort2*>(out + (size_t)r * cD + lane * 2) = o;
}

// (x0 + x1 + x2)/3 at gathered rows -> LayerNorm -> dst (x1,x2 bf16)
__global__ __launch_bounds__(128) void gather_ln(
    const int* __restrict__ ids, int mode,
    const float* __restrict__ ea, const float* __restrict__ eb, int na,
    const ushort* __restrict__ x1, const ushort* __restrict__ x2, const int* __restrict__ slot,
    const float* __restrict__ g, const float* __restrict__ bia, float* __restrict__ dst) {
  __shared__ float shx[2], shy[2];
  int i = blockIdx.x;
  int tid = threadIdx.x;
  int id = ids[i];
  int node = mapNode(mode, id);
  if (node < 0) return;
  const float* x0 = (node < na) ? (ea + (size_t)node * cD) : (eb + (size_t)(node - na) * cD);
  int xi2 = slot ? slot[node] : node;
  float a = (x0[tid] + bf2f(x1[(size_t)node * cD + tid]) + bf2f(x2[(size_t)xi2 * cD + tid]))
            * (1.0f / 3.0f);
  float sx = a, sy = a * a;
#pragma unroll
  for (int off = 32; off > 0; off >>= 1) {
    sx += __shfl_xor(sx, off);
    sy += __shfl_xor(sy, off);
  }
  if ((tid & 63) == 0) { shx[tid >> 6] = sx; shy[tid >> 6] = sy; }
  __syncthreads();
  float s  = shx[0] + shx[1];
  float ss = shy[0] + shy[1];
  float mu = s * (1.0f / 128.0f);
  float var = ss * (1.0f / 128.0f) - mu * mu;
  float y = (a - mu) * rsqrtf(var + 1e-5f) * g[tid] + bia[tid];
  dst[(size_t)i * cD + tid] = y;
}

// batched t2c LayerNorm: blockIdx.y=0 -> mode1 into S1; =1 -> mode2 into S2
__global__ __launch_bounds__(128) void gather_ln_t2(
    const int* __restrict__ ids,
    const float* __restrict__ type_e, const float* __restrict__ cluster,
    const ushort* __restrict__ x1, const ushort* __restrict__ x2,
    const float* __restrict__ g, const float* __restrict__ bia,
    float* __restrict__ s1, float* __restrict__ s2) {
  __shared__ float shx[2], shy[2];
  int z = blockIdx.y;
  int mode = z ? 2 : 1;
  float* dst = z ? s2 : s1;
  int i = blockIdx.x;
  int tid = threadIdx.x;
  int id = ids[i];
  int node = mapNode(mode, id);
  if (node < 0) return;
  const float* x0 = (node < cNT) ? (type_e + (size_t)node * cD)
                                 : (cluster + (size_t)(node - cNT) * cD);
  float a = (x0[tid] + bf2f(x1[(size_t)node * cD + tid]) + bf2f(x2[(size_t)node * cD + tid]))
            * (1.0f / 3.0f);
  float sx = a, sy = a * a;
#pragma unroll
  for (int off = 32; off > 0; off >>= 1) {
    sx += __shfl_xor(sx, off);
    sy += __shfl_xor(sy, off);
  }
  if ((tid & 63) == 0) { shx[tid >> 6] = sx; shy[tid >> 6] = sy; }
  __syncthreads();
  float s  = shx[0] + shx[1];
  float ss = shy[0] + shy[1];
  float mu = s * (1.0f / 128.0f);
  float var = ss * (1.0f / 128.0f) - mu * mu;
  float y = (a - mu) * rsqrtf(var + 1e-5f) * g[tid] + bia[tid];
  dst[(size_t)i * cD + tid] = y;
}

// ---------------------------------------------------------------------------
// bf16 MFMA GEMM: C[M,N] = A[M,K] @ Bt[N,K]^T, 128x128 tile, 4 waves
// ---------------------------------------------------------------------------
__global__ __launch_bounds__(256) void gemm_bf(
    const ushort* __restrict__ A, const ushort* __restrict__ Bt,
    int N, int K, const float* __restrict__ bias, ushort* __restrict__ Cbf, int epi) {
  __shared__ ushort As[128 * 40];
  __shared__ ushort Bs[128 * 40];
  const int bx = blockIdx.x, by = blockIdx.y;
  const int t = threadIdx.x;
  const int wv = t >> 6, lane = t & 63;
  const int wr = (wv >> 1) * 64, wc = (wv & 1) * 64;
  const int srow = t >> 1, shalf = t & 1;
  const ushort* Ag = A + (size_t)(by * 128 + srow) * K + shalf * 16;
  const ushort* Bg = Bt + (size_t)(bx * 128 + srow) * K + shalf * 16;
  uint4 ra0 = *reinterpret_cast<const uint4*>(Ag);
  uint4 ra1 = *reinterpret_cast<const uint4*>(Ag + 8);
  uint4 rb0 = *reinterpret_cast<const uint4*>(Bg);
  uint4 rb1 = *reinterpret_cast<const uint4*>(Bg + 8);
  f32x4 acc[4][4];
  const f32x4 z4 = {0.f, 0.f, 0.f, 0.f};
#pragma unroll
  for (int i = 0; i < 4; ++i)
#pragma unroll
    for (int j = 0; j < 4; ++j) acc[i][j] = z4;
  const int la = lane & 15, lk = (lane >> 4) * 8;
  const int sdst = srow * 40 + shalf * 16;
  for (int kt = 0; kt < K; kt += 32) {
    __syncthreads();
    *reinterpret_cast<uint4*>(&As[sdst])     = ra0;
    *reinterpret_cast<uint4*>(&As[sdst + 8]) = ra1;
    *reinterpret_cast<uint4*>(&Bs[sdst])     = rb0;
    *reinterpret_cast<uint4*>(&Bs[sdst + 8]) = rb1;
    __syncthreads();
    if (kt + 32 < K) {
      ra0 = *reinterpret_cast<const uint4*>(Ag + kt + 32);
      ra1 = *reinterpret_cast<const uint4*>(Ag + kt + 40);
      rb0 = *reinterpret_cast<const uint4*>(Bg + kt + 32);
      rb1 = *reinterpret_cast<const uint4*>(Bg + kt + 40);
    }
    short8v af[4], bfr[4];
#pragma unroll
    for (int i = 0; i < 4; ++i)
      af[i] = *reinterpret_cast<const short8v*>(&As[(wr + i * 16 + la) * 40 + lk]);
#pragma unroll
    for (int j = 0; j < 4; ++j)
      bfr[j] = *reinterpret_cast<const short8v*>(&Bs[(wc + j * 16 + la) * 40 + lk]);
#pragma unroll
    for (int i = 0; i < 4; ++i)
#pragma unroll
      for (int j = 0; j < 4; ++j)
        acc[i][j] = __builtin_amdgcn_mfma_f32_16x16x32_bf16(af[i], bfr[j], acc[i][j], 0, 0, 0);
  }
  const int r0 = by * 128 + wr + (lane >> 4) * 4;
  const int c0 = bx * 128 + wc + la;
#pragma unroll
  for (int i = 0; i < 4; ++i)
#pragma unroll
    for (int j = 0; j < 4; ++j) {
      int c = c0 + j * 16;
      float bv = bias[c];
#pragma unroll
      for (int q = 0; q < 4; ++q) {
        int r = r0 + i * 16 + q;
        float v = acc[i][j][q] + bv;
        if (epi == 1) v = (v > 0.0f) ? v : expm1f(v);
        Cbf[(size_t)r * N + c] = f2bf(v);
      }
    }
}

// ---------------------------------------------------------------------------
// Fused gate + pooling (per mailbox)
// ---------------------------------------------------------------------------
__global__ __launch_bounds__(256) void k_gate_pool(
    const ushort* __restrict__ o, const float* __restrict__ gw,
    ushort* __restrict__ ae, float* __restrict__ gsum) {
  __shared__ float os[8][1024];
  __shared__ float lg[8][4];
  __shared__ float gs[8][4];
  const int b = blockIdx.x, t = threadIdx.x;
  for (int u = t; u < 8192; u += 256) {
    int l = u >> 10, d = u & 1023;
    os[l][d] = bf2f(o[(size_t)(b * 8 + l) * 1024 + d]);
  }
  __syncthreads();
  {
    int p = t >> 3, sub = t & 7;
    int l = p >> 2, e = p & 3;
    float s = 0;
    for (int d = sub; d < 1024; d += 8) s += os[l][d] * gw[d * 4 + e];
    s += __shfl_down(s, 4, 8);
    s += __shfl_down(s, 2, 8);
    s += __shfl_down(s, 1, 8);
    if (sub == 0) lg[l][e] = s;
  }
  __syncthreads();
  if (t < 8) {
    float m = fmaxf(fmaxf(lg[t][0], lg[t][1]), fmaxf(lg[t][2], lg[t][3]));
    float e0 = expf(lg[t][0] - m), e1 = expf(lg[t][1] - m);
    float e2 = expf(lg[t][2] - m), e3 = expf(lg[t][3] - m);
    float inv = 1.0f / (e0 + e1 + e2 + e3);
    gs[t][0] = e0 * inv; gs[t][1] = e1 * inv;
    gs[t][2] = e2 * inv; gs[t][3] = e3 * inv;
  }
  __syncthreads();
  if (t < 4) {
    float g = 0;
#pragma unroll
    for (int l = 0; l < 8; ++l) g += gs[l][t];
    gsum[b * 4 + t] = g;
  }
#pragma unroll
  for (int rep = 0; rep < 4; ++rep) {
    int d = t + rep * 256;
    float a0 = 0, a1 = 0, a2 = 0, a3 = 0;
#pragma unroll
    for (int l = 0; l < 8; ++l) {
      float ov = os[l][d];
      a0 += gs[l][0] * ov; a1 += gs[l][1] * ov;
      a2 += gs[l][2] * ov; a3 += gs[l][3] * ov;
    }
    ae[(size_t)0 * 524288 + b * 1024 + d] = f2bf(a0);
    ae[(size_t)1 * 524288 + b * 1024 + d] = f2bf(a1);
    ae[(size_t)2 * 524288 + b * 1024 + d] = f2bf(a2);
    ae[(size_t)3 * 524288 + b * 1024 + d] = f2bf(a3);
  }
}

// ---------------------------------------------------------------------------
// Pooled MoE GEMM (experts folded into K-accumulation)
// ---------------------------------------------------------------------------
__global__ __launch_bounds__(256) void gemm_moe2(
    const ushort* __restrict__ AE, const ushort* __restrict__ Bt4,
    const float* __restrict__ expb, const float* __restrict__ gsum,
    float* __restrict__ out) {
  __shared__ ushort As[64 * 40];
  __shared__ ushort Bs[64 * 40];
  const int bx = blockIdx.x, by = blockIdx.y;
  const int t = threadIdx.x;
  const int wv = t >> 6, lane = t & 63;
  const int wr = (wv >> 1) * 32, wc = (wv & 1) * 32;
  const int srow = t >> 2, sq = t & 3;
  const int la = lane & 15, lk = (lane >> 4) * 8;
  const int sdst = srow * 40 + sq * 8;
  f32x4 acc[2][2];
  const f32x4 z4 = {0.f, 0.f, 0.f, 0.f};
  acc[0][0] = z4; acc[0][1] = z4; acc[1][0] = z4; acc[1][1] = z4;
  for (int e = 0; e < 4; ++e) {
    const ushort* Ag = AE + (size_t)e * 524288 + (size_t)(by * 64 + srow) * 1024 + sq * 8;
    const ushort* Bg = Bt4 + (size_t)e * 1048576 + (size_t)(bx * 64 + srow) * 1024 + sq * 8;
    uint4 ra = *reinterpret_cast<const uint4*>(Ag);
    uint4 rb = *reinterpret_cast<const uint4*>(Bg);
    for (int kt = 0; kt < 1024; kt += 32) {
      __syncthreads();
      *reinterpret_cast<uint4*>(&As[sdst]) = ra;
      *reinterpret_cast<uint4*>(&Bs[sdst]) = rb;
      __syncthreads();
      if (kt + 32 < 1024) {
        ra = *reinterpret_cast<const uint4*>(Ag + kt + 32);
        rb = *reinterpret_cast<const uint4*>(Bg + kt + 32);
      }
      short8v af[2], bfr[2];
#pragma unroll
      for (int i = 0; i < 2; ++i)
        af[i] = *reinterpret_cast<const short8v*>(&As[(wr + i * 16 + la) * 40 + lk]);
#pragma unroll
      for (int j = 0; j < 2; ++j)
        bfr[j] = *reinterpret_cast<const short8v*>(&Bs[(wc + j * 16 + la) * 40 + lk]);
#pragma unroll
      for (int i = 0; i < 2; ++i)
#pragma unroll
        for (int j = 0; j < 2; ++j)
          acc[i][j] = __builtin_amdgcn_mfma_f32_16x16x32_bf16(af[i], bfr[j], acc[i][j], 0, 0, 0);
    }
  }
  const int r0 = by * 64 + wr + (lane >> 4) * 4;
  const int c0 = bx * 64 + wc + la;
#pragma unroll
  for (int i = 0; i < 2; ++i)
#pragma unroll
    for (int q = 0; q < 4; ++q) {
      int r = r0 + i * 16 + q;
      float4 gv = *reinterpret_cast<const float4*>(gsum + r * 4);
#pragma unroll
      for (int j = 0; j < 2; ++j) {
        int c = c0 + j * 16;
        float bias = gv.x * expb[c] + gv.y * expb[1024 + c] +
                     gv.z * expb[2048 + c] + gv.w * expb[3072 + c];
        float s = (acc[i][j][q] + bias) * 0.125f;
        out[(size_t)r * 1024 + c] = 1.0f / (1.0f + expf(-s));
      }
    }
}

// ---------------------------------------------------------------------------
// Symmetric Gram contrastive kernel (2080 triangular tiles) — proven form
// ---------------------------------------------------------------------------
__global__ __launch_bounds__(256) void gram_sym(
    const ushort* __restrict__ W, float* __restrict__ rsum,
    float* __restrict__ d11, float* __restrict__ d12, float* __restrict__ d22) {
  __shared__ ushort As[128 * 40];
  __shared__ ushort Bs[128 * 40];
  int tt = blockIdx.x, bi = 0, cnt = 64;
  while (tt >= cnt) { tt -= cnt; ++bi; --cnt; }
  int bj = bi + tt;
  const bool diag = (bi == bj);
  const int t = threadIdx.x;
  const int wv = t >> 6, lane = t & 63;
  const int wr = (wv >> 1) * 64, wc = (wv & 1) * 64;
  const int srow = t >> 1, shalf = t & 1;
  const ushort* Ag = W + (size_t)(bi * 128 + srow) * 128 + shalf * 16;
  const ushort* Bg = W + (size_t)(bj * 128 + srow) * 128 + shalf * 16;
  uint4 ra0 = *reinterpret_cast<const uint4*>(Ag);
  uint4 ra1 = *reinterpret_cast<const uint4*>(Ag + 8);
  uint4 rb0 = *reinterpret_cast<const uint4*>(Bg);
  uint4 rb1 = *reinterpret_cast<const uint4*>(Bg + 8);
  f32x4 acc[4][4];
  const f32x4 z4 = {0.f, 0.f, 0.f, 0.f};
#pragma unroll
  for (int i = 0; i < 4; ++i)
#pragma unroll
    for (int j = 0; j < 4; ++j) acc[i][j] = z4;
  const int la = lane & 15, lk = (lane >> 4) * 8;
  const int sdst = srow * 40 + shalf * 16;
  for (int kt = 0; kt < 128; kt += 32) {
    __syncthreads();
    *reinterpret_cast<uint4*>(&As[sdst])     = ra0;
    *reinterpret_cast<uint4*>(&As[sdst + 8]) = ra1;
    *reinterpret_cast<uint4*>(&Bs[sdst])     = rb0;
    *reinterpret_cast<uint4*>(&Bs[sdst + 8]) = rb1;
    __syncthreads();
    if (kt + 32 < 128) {
      ra0 = *reinterpret_cast<const uint4*>(Ag + kt + 32);
      ra1 = *reinterpret_cast<const uint4*>(Ag + kt + 40);
      rb0 = *reinterpret_cast<const uint4*>(Bg + kt + 32);
      rb1 = *reinterpret_cast<const uint4*>(Bg + kt + 40);
    }
    short8v af[4], bfr[4];
#pragma unroll
    for (int i = 0; i < 4; ++i)
      af[i] = *reinterpret_cast<const short8v*>(&As[(wr + i * 16 + la) * 40 + lk]);
#pragma unroll
    for (int j = 0; j < 4; ++j)
      bfr[j] = *reinterpret_cast<const short8v*>(&Bs[(wc + j * 16 + la) * 40 + lk]);
#pragma unroll
    for (int i = 0; i < 4; ++i)
#pragma unroll
      for (int j = 0; j < 4; ++j)
        acc[i][j] = __builtin_amdgcn_mfma_f32_16x16x32_bf16(af[i], bfr[j], acc[i][j], 0, 0, 0);
  }
  const int r0 = bi * 128 + wr + (lane >> 4) * 4;
  const int c0 = bj * 128 + wc + la;
  constexpr float K2 = 2.8853900817779268f;   // 2 / ln(2)
  float rs[4][4];
  float cs[4] = {0.f, 0.f, 0.f, 0.f};
#pragma unroll
  for (int i = 0; i < 4; ++i)
#pragma unroll
    for (int q = 0; q < 4; ++q) rs[i][q] = 0.f;
#pragma unroll
  for (int i = 0; i < 4; ++i)
#pragma unroll
    for (int j = 0; j < 4; ++j)
#pragma unroll
      for (int q = 0; q < 4; ++q) {
        int r = r0 + i * 16 + q;
        int c = c0 + j * 16;
        float e = exp2f(K2 * acc[i][j][q]);
        rs[i][q] += e;
        cs[j] += e;
        if (c == r)        { if (r < 4096) d11[r] = e; else d22[r - 4096] = e; }
        if (c == r + 4096) d12[r] = e;
      }
#pragma unroll
  for (int m = 1; m < 16; m <<= 1)
#pragma unroll
    for (int i = 0; i < 4; ++i)
#pragma unroll
      for (int q = 0; q < 4; ++q) rs[i][q] += __shfl_xor(rs[i][q], m);
  float* rowdst = rsum + ((bj >= 32) ? 8192 : 0);
  if (la == 0) {
#pragma unroll
    for (int i = 0; i < 4; ++i)
#pragma unroll
      for (int q = 0; q < 4; ++q) atomAdd(&rowdst[r0 + i * 16 + q], rs[i][q]);
  }
  if (!diag) {
#pragma unroll
    for (int j = 0; j < 4; ++j) {
      cs[j] += __shfl_xor(cs[j], 16);
      cs[j] += __shfl_xor(cs[j], 32);
    }
    float* coldst = rsum + ((bi >= 32) ? 8192 : 0);
    if ((lane >> 4) == 0) {
#pragma unroll
      for (int j = 0; j < 4; ++j) atomAdd(&coldst[c0 + j * 16], cs[j]);
    }
  }
}

__global__ __launch_bounds__(256) void cl_row(
    const float* __restrict__ rsum, const float* __restrict__ d11,
    const float* __restrict__ d12, const float* __restrict__ d22,
    float* __restrict__ cl_sum) {
  __shared__ float sh[256];
  int i = blockIdx.x * 256 + threadIdx.x;
  float denA = rsum[i] + rsum[8192 + i] - d11[i];
  float denB = rsum[8192 + 4096 + i] + rsum[4096 + i] - d22[i];
  float l = 0.5f * (logf(denA) + logf(denB)) - logf(d12[i]);
  float s = blockReduce256(l, sh, threadIdx.x);
  if (threadIdx.x == 0) atomAdd(cl_sum, s);
}

// weight transpose + bf16 convert: Bt[n*K+k] = bf16(W[k*N+n])
__global__ __launch_bounds__(256) void k_wt_bt(const float* __restrict__ W,
                                               ushort* __restrict__ Bt, int K, int N) {
  __shared__ float tile[32][33];
  int n0 = blockIdx.x * 32, k0 = blockIdx.y * 32;
  int tx = threadIdx.x & 31, ty = threadIdx.x >> 5;
#pragma unroll
  for (int i = 0; i < 4; ++i)
    tile[ty + 8 * i][tx] = W[(size_t)(k0 + ty + 8 * i) * N + n0 + tx];
  __syncthreads();
#pragma unroll
  for (int i = 0; i < 4; ++i)
    Bt[(size_t)(n0 + ty + 8 * i) * K + k0 + tx] = f2bf(tile[tx][ty + 8 * i]);
}

// batched transpose: W strided by z
__global__ __launch_bounds__(256) void k_wt_bt_s(const float* __restrict__ Wbase,
                                                 ushort* __restrict__ Btbase, int K, int N) {
  __shared__ float tile[32][33];
  const float* W = Wbase + (size_t)blockIdx.z * K * N;
  ushort* Bt = Btbase + (size_t)blockIdx.z * K * N;
  int n0 = blockIdx.x * 32, k0 = blockIdx.y * 32;
  int tx = threadIdx.x & 31, ty = threadIdx.x >> 5;
#pragma unroll
  for (int i = 0; i < 4; ++i)
    tile[ty + 8 * i][tx] = W[(size_t)(k0 + ty + 8 * i) * N + n0 + tx];
  __syncthreads();
#pragma unroll
  for (int i = 0; i < 4; ++i)
    Bt[(size_t)(n0 + ty + 8 * i) * K + k0 + tx] = f2bf(tile[tx][ty + 8 * i]);
}

// batched transpose for 4 separate weight pointers (QKV + O)
__global__ __launch_bounds__(256) void k_wt_bt4(const float* __restrict__ w0,
                                                const float* __restrict__ w1,
                                                const float* __restrict__ w2,
                                                const float* __restrict__ w3,
                                                ushort* __restrict__ Btbase, int K, int N) {
  __shared__ float tile[32][33];
  const float* W = (blockIdx.z == 0) ? w0 : (blockIdx.z == 1) ? w1
                 : (blockIdx.z == 2) ? w2 : w3;
  ushort* Bt = Btbase + (size_t)blockIdx.z * K * N;
  int n0 = blockIdx.x * 32, k0 = blockIdx.y * 32;
  int tx = threadIdx.x & 31, ty = threadIdx.x >> 5;
#pragma unroll
  for (int i = 0; i < 4; ++i)
    tile[ty + 8 * i][tx] = W[(size_t)(k0 + ty + 8 * i) * N + n0 + tx];
  __syncthreads();
#pragma unroll
  for (int i = 0; i < 4; ++i)
    Bt[(size_t)(n0 + ty + 8 * i) * K + k0 + tx] = f2bf(tile[tx][ty + 8 * i]);
}

// ---------------------------------------------------------------------------
// Fused S post-process: SB bf16 write + MSG build + emb_sum partial.
// ---------------------------------------------------------------------------
__global__ __launch_bounds__(256) void k_post_s(
    const float* __restrict__ s1, const float* __restrict__ s2,
    const float* __restrict__ relation, const int* __restrict__ etype,
    ushort* __restrict__ sb, ushort* __restrict__ msg, float* __restrict__ emb_out) {
  __shared__ float sh[256];
  float part = 0.f;
  for (int idx = blockIdx.x * 256 + threadIdx.x; idx < 1048576; idx += 128 * 256) {
    float vs = (idx < 524288) ? s1[idx] : s2[idx - 524288];
    sb[idx] = f2bf(vs);
    int i = idx >> 8, j = idx & 255;
    int et = etype[i];
    float sign = (et >= cNR) ? -1.0f : 1.0f;
    float r = relation[(size_t)(et % cNR) * 256 + j];
    float s = (j < 128) ? s1[(size_t)i * 128 + j] : s2[(size_t)i * 128 + j - 128];
    msg[idx] = f2bf(fmaxf(s + r * sign, 0.0f));
    part += s * s + r * r;
  }
  float tot = blockReduce256(part, sh, threadIdx.x);
  if (threadIdx.x == 0) atomAdd(emb_out, tot);
}

// in-place bf16 row normalize (wave reduction, 1 sync)
__global__ __launch_bounds__(128) void rownorm_bf2(ushort* __restrict__ w) {
  __shared__ float sh[2];
  int i = blockIdx.x, tid = threadIdx.x;
  float v = bf2f(w[(size_t)i * cD + tid]);
  float ss = v * v;
#pragma unroll
  for (int off = 32; off > 0; off >>= 1) ss += __shfl_xor(ss, off);
  if ((tid & 63) == 0) sh[tid >> 6] = ss;
  __syncthreads();
  float n = fmaxf(sqrtf(sh[0] + sh[1]), 1e-12f);
  w[(size_t)i * cD + tid] = f2bf(v / n);
}

// fused-QKV attention: qkv [4096][3072], o [4096][1024] bf16
__global__ __launch_bounds__(64) void mha_attn(
    const ushort* __restrict__ qkv, ushort* __restrict__ o) {
  __shared__ float qs[8][132], ks[8][132], vs[8][132];
  __shared__ float att[8][8];
  int bh = blockIdx.x;
  int b = bh >> 3, h = bh & 7;
  int tid = threadIdx.x;
  for (int u = tid; u < 256; u += 64) {
    int l = u >> 5;
    int d4 = (u & 31) * 4;
    size_t base = (size_t)(b * 8 + l) * 3072 + h * 128 + d4;
    ushort4 qv = *reinterpret_cast<const ushort4*>(qkv + base);
    ushort4 kv = *reinterpret_cast<const ushort4*>(qkv + base + 1024);
    ushort4 vv = *reinterpret_cast<const ushort4*>(qkv + base + 2048);
    qs[l][d4] = bf2f(qv.x); qs[l][d4 + 1] = bf2f(qv.y);
    qs[l][d4 + 2] = bf2f(qv.z); qs[l][d4 + 3] = bf2f(qv.w);
    ks[l][d4] = bf2f(kv.x); ks[l][d4 + 1] = bf2f(kv.y);
    ks[l][d4 + 2] = bf2f(kv.z); ks[l][d4 + 3] = bf2f(kv.w);
    vs[l][d4] = bf2f(vv.x); vs[l][d4 + 1] = bf2f(vv.y);
    vs[l][d4 + 2] = bf2f(vv.z); vs[l][d4 + 3] = bf2f(vv.w);
  }
  __syncthreads();
  int l = tid >> 3, m = tid & 7;
  const float4* qp = reinterpret_cast<const float4*>(&qs[l][0]);
  const float4* kp = reinterpret_cast<const float4*>(&ks[m][0]);
  float s = 0;
#pragma unroll
  for (int d4 = 0; d4 < 32; ++d4) {
    float4 a = qp[d4], bb = kp[d4];
    s += a.x * bb.x + a.y * bb.y + a.z * bb.z + a.w * bb.w;
  }
  s *= 0.08838834764831845f;
  float mx = s;
  for (int off = 1; off < 8; off <<= 1) mx = fmaxf(mx, __shfl_xor(mx, off, 8));
  float p = expf(s - mx);
  float sum = p;
  for (int off = 1; off < 8; off <<= 1) sum += __shfl_xor(sum, off, 8);
  att[l][m] = p / sum;
  __syncthreads();
  for (int u = tid; u < 1024; u += 64) {
    int ll = u >> 7, d = u & 127;
    float acc = 0;
#pragma unroll
    for (int mm = 0; mm < 8; ++mm) acc += att[ll][mm] * vs[mm][d];
    o[(size_t)(b * 8 + ll) * 1024 + h * 128 + d] = f2bf(acc);
  }
}

__global__ void finalize_k(const float* __restrict__ scal, float* __restrict__ out_aux) {
  float cl = scal[0] * (1.0f / cNSRC);
  float emb = cDECAY * 0.5f * scal[1] * (1.0f / cNSRC);
  out_aux[0] = cCLW * cl + emb;
}

// ---------------------------------------------------------------------------
// Launch
// ---------------------------------------------------------------------------
extern "C" void kernel_launch(void* const* d_in, const int* in_sizes, int n_in,
                              void* d_out, int out_size, void* d_ws, size_t ws_size,
                              hipStream_t stream) {
  (void)in_sizes; (void)n_in; (void)out_size; (void)ws_size;
  const float* entity   = (const float*)d_in[0];
  const float* type_e   = (const float*)d_in[1];
  const float* cluster  = (const float*)d_in[2];
  const float* relation = (const float*)d_in[3];
  const float* ln_g  = (const float*)d_in[4];
  const float* ln_b  = (const float*)d_in[5];
  const float* cl_w1 = (const float*)d_in[6];
  const float* cl_b1 = (const float*)d_in[7];
  const float* cl_w2 = (const float*)d_in[8];
  const float* cl_b2 = (const float*)d_in[9];
  const float* fc_w  = (const float*)d_in[10];
  const float* fc_b  = (const float*)d_in[11];
  const float* wq = (const float*)d_in[12];
  const float* bq = (const float*)d_in[13];
  const float* wk = (const float*)d_in[14];
  const float* bk = (const float*)d_in[15];
  const float* wv = (const float*)d_in[16];
  const float* bv = (const float*)d_in[17];
  const float* wo = (const float*)d_in[18];
  const float* bo = (const float*)d_in[19];
  const float* gate_w = (const float*)d_in[20];
  const float* exp_w  = (const float*)d_in[21];
  const float* exp_b  = (const float*)d_in[22];
  const float* e2t_val = (const float*)d_in[23];
  const float* t2c_val = (const float*)d_in[24];
  const float* e2c_val = (const float*)d_in[25];
  const int* e2t_row = (const int*)d_in[26];
  const int* e2t_col = (const int*)d_in[27];
  const int* t2c_row = (const int*)d_in[28];
  const int* t2c_col = (const int*)d_in[29];
  const int* e2c_row = (const int*)d_in[30];
  const int* e2c_col = (const int*)d_in[31];
  const int* src_ids = (const int*)d_in[32];
  const int* etype   = (const int*)d_in[33];

  float* ws = (float*)d_ws;
  float* S1 = ws + F_S1;
  float* S2 = ws + F_S2;
  ushort* Wbf = (ushort*)(ws + F_PT);
  ushort* P1bf = (ushort*)(ws + F_Z1);
  ushort* SBbf = (ushort*)(ws + F_Z2);
  ushort* MSGbf = (ushort*)(ws + F_MSG);
  float* GSUM = ws + F_GATE;
  float* SCAL = ws + F_SCAL;
  float* RS   = ws + F_RS;
  float* BQKV = ws + F_GATE + 8192;
  float* D11  = ws + F_D11;
  float* D12  = ws + F_D12;
  float* D22  = ws + F_D22;
  ushort* X1F = (ushort*)(ws + G_X1F);
  ushort* X2C = (ushort*)(ws + G_X2C);
  int*   SLOTb = (int*)(ws + G_SLOT);
  int*   MARKb = (int*)(ws + G_MARK);
  int*   REPb  = (int*)(ws + G_REP);
  int*   RPb   = (int*)(ws + G_RP);
  int*   FILLb = (int*)(ws + G_FILL);
  int*   BSUMb = (int*)(ws + G_BSUM);
  int*   COLSb = (int*)(ws + G_COLS);
  float* VALSb = ws + G_VALS;
  ushort* X1T = (ushort*)(ws + G_X1T);
  ushort* X2T = (ushort*)(ws + G_X2T);
  ushort* EBF = (ushort*)(ws + G_EBF);
  ushort* TBF = (ushort*)(ws + G_TBF);
  ushort* CBF = (ushort*)(ws + G_CBF);
  ushort* PB   = (ushort*)(ws + A_U0);
  ushort* AE   = (ushort*)(ws + A_U0);
  ushort* QKV  = (ushort*)(ws + A_U1);
  ushort* OB   = (ushort*)(ws + A_U1);
  ushort* WBT  = (ushort*)(ws + A_WBT);

  hipMemsetAsync(SCAL, 0, 2 * sizeof(float), stream);
  hipMemsetAsync(RS, 0, (16384 + 3 * 4096) * sizeof(float), stream);

  // ---- bf16 embedding tables (one fused launch) ----
  k_to_bf3<<<2048, 256, 0, stream>>>(entity, type_e, cluster, EBF, TBF, CBF);

  // ---- z-batched CSR build for all three graphs ----
  const int gEdgeMax = (cNNZ_E2T + 255) / 256;   // 3907
  const int nbMax = 396;
  k_csr_init3<<<dim3(nbMax, 1, 3), 256, 0, stream>>>(SLOTb, MARKb, FILLb);
  k_slot_mark2<<<dim3(16, 1, 2), 256, 0, stream>>>(src_ids, SLOTb, MARKb);
  k_mark_edges2<<<dim3(gEdgeMax, 1, 2), 256, 0, stream>>>(e2t_row, e2t_col,
                                                          e2c_row, e2c_col, SLOTb, MARKb);
  k_hist3<<<dim3(gEdgeMax, 1, 3), 256, 0, stream>>>(e2t_row, e2c_row, t2c_row, MARKb, FILLb);
  k_scan_block3<<<dim3(nbMax, 1, 3), 256, 0, stream>>>(FILLb, RPb, BSUMb);
  k_bsum_scan3<<<3, 512, 0, stream>>>(BSUMb, RPb);
  k_scan_add3<<<dim3(nbMax, 1, 3), 256, 0, stream>>>(RPb, BSUMb, FILLb);
  k_fill3<<<dim3(gEdgeMax, 1, 3), 256, 0, stream>>>(e2t_row, e2t_col, e2t_val,
                                                    e2c_row, e2c_col, e2c_val,
                                                    t2c_row, t2c_col, t2c_val,
                                                    MARKb, FILLb, COLSb, VALSb);
  k_rep2<<<dim3(16, 1, 2), 256, 0, stream>>>(src_ids, SLOTb, REPb);

  // ---- e2t: gather + slot gather + LN -> S1 ----
  k_gather<<<(cNN_E2T + 3) / 4, 256, 0, stream>>>(RPb, COLSb + CO_E2T, VALSb + CO_E2T,
                                                  EBF, TBF, cNE, cNN_E2T, MARKb, X1F);
  k_gather_slot<<<cNSRC / 4, 256, 0, stream>>>(RPb, COLSb + CO_E2T, VALSb + CO_E2T,
                                               X1F, REPb, X2C);
  gather_ln<<<cNSRC, 128, 0, stream>>>(src_ids, 0, entity, type_e, cNE, X1F, X2C, SLOTb,
                                       ln_g, ln_b, S1);

  // ---- e2c: gather + slot gather + LN -> S2 ----
  k_gather<<<(cNN_E2C + 3) / 4, 256, 0, stream>>>(RPb + RP_STR, COLSb + CO_E2C, VALSb + CO_E2C,
                                                  EBF, CBF, cNE, cNN_E2C,
                                                  MARKb + SL_STR, X1F);
  k_gather_slot<<<cNSRC / 4, 256, 0, stream>>>(RPb + RP_STR, COLSb + CO_E2C, VALSb + CO_E2C,
                                               X1F, REPb + 4096, X2C);
  gather_ln<<<cNSRC, 128, 0, stream>>>(src_ids, 3, entity, cluster, cNE, X1F, X2C,
                                       SLOTb + SL_STR, ln_g, ln_b, S2);

  // ---- t2c: full gathers + batched LN (modes 1,2) ----
  k_gather<<<(cNN_T2C + 3) / 4, 256, 0, stream>>>(RPb + 2 * RP_STR, COLSb + CO_T2C,
                                                  VALSb + CO_T2C, TBF, CBF, cNT,
                                                  cNN_T2C, nullptr, X1T);
  k_gather_bf<<<(cNN_T2C + 3) / 4, 256, 0, stream>>>(RPb + 2 * RP_STR, COLSb + CO_T2C,
                                                     VALSb + CO_T2C, X1T, cNN_T2C, X2T);
  gather_ln_t2<<<dim3(cNSRC, 2), 128, 0, stream>>>(src_ids, type_e, cluster, X1T, X2T,
                                                   ln_g, ln_b, S1, S2);

  // ================= fused S post-process (SB + MSG + emb_sum) =================
  k_post_s<<<128, 256, 0, stream>>>(S1, S2, relation, etype, SBbf, MSGbf, SCAL + 1);

  // ================= contrastive loss =================
  ushort* W1T = WBT;
  ushort* W2T = WBT + 16384;
  k_wt_bt<<<dim3(4, 4), 256, 0, stream>>>(cl_w1, W1T, cD, cD);
  k_wt_bt<<<dim3(4, 4), 256, 0, stream>>>(cl_w2, W2T, cD, cD);
  gemm_bf<<<dim3(1, 64), 256, 0, stream>>>(SBbf, W1T, cD, cD, cl_b1, P1bf, 1);
  gemm_bf<<<dim3(1, 64), 256, 0, stream>>>(P1bf, W2T, cD, cD, cl_b2, Wbf, 0);
  rownorm_bf2<<<2 * cNSRC, 128, 0, stream>>>(Wbf);
  gram_sym<<<2080, 256, 0, stream>>>(Wbf, RS, D11, D12, D22);
  cl_row<<<16, 256, 0, stream>>>(RS, D11, D12, D22, SCAL);

  // ================= predict =================
  k_wt_bt<<<dim3(cT / 32, 256 / 32), 256, 0, stream>>>(fc_w, WBT, 256, cT);
  gemm_bf<<<dim3(cT / 128, cNSRC / 128), 256, 0, stream>>>(MSGbf, WBT, cT, 256, fc_b, PB, 0);

  // ================= MHA: fused QKV (+O weight pre-transposed) =================
  k_wt_bt4<<<dim3(32, 32, 4), 256, 0, stream>>>(wq, wk, wv, wo, WBT, cT, cT);
  k_pack_bias<<<12, 256, 0, stream>>>(bq, bk, bv, BQKV);
  gemm_bf<<<dim3(3072 / 128, cNSRC / 128), 256, 0, stream>>>(PB, WBT, 3072, cT, BQKV, QKV, 0);
  mha_attn<<<cB * 8, 64, 0, stream>>>(QKV, PB);
  gemm_bf<<<dim3(cT / 128, cNSRC / 128), 256, 0, stream>>>(PB, WBT + 3 * 1048576, cT, cT,
                                                           bo, OB, 0);

  // ================= pooled MoE =================
  k_gate_pool<<<cB, 256, 0, stream>>>(OB, gate_w, AE, GSUM);
  k_wt_bt_s<<<dim3(32, 32, 4), 256, 0, stream>>>(exp_w, WBT, cT, cT);
  gemm_moe2<<<dim3(16, 8), 256, 0, stream>>>(AE, WBT, exp_b, GSUM, (float*)d_out);

  finalize_k<<<1, 1, 0, stream>>>(SCAL, (float*)d_out + (size_t)cB * cT);
}